// Round 6
// baseline (473.421 us; speedup 1.0000x reference)
//
#include <hip/hip_runtime.h>

// VectorQuantizer forward, MI355X. Split-bf16 MFMA GEMM (hi/lo, 3 products,
// K extended 256->768), single accumulator. Epilogue: argmin + per-block
// online-softmax partials (exact entropy) + racy-shrinking-threshold candidate
// capture. d^2-norm split (vqkd/vqgan) computed in CLOSED FORM via Gram
// matrices + column sums + scalar moments (R5's bf16 dk stash spilled ~900MB
// to scratch). T=4096 tokens, NE=16384 codes.

#define T_TOK 4096
#define NE    16384
#define KD    256
#define K3    768          // 3x split-extended K
#define CAP   768          // candidate slots per token (avg_probs only)
#define DCUT  0.15f        // capture window above best-so-far global min

typedef __attribute__((ext_vector_type(8))) short bf16x8;
typedef __attribute__((ext_vector_type(4))) float f32x4;
typedef unsigned long long u64;

__device__ __forceinline__ short f2bf(float f) {
    unsigned u = __float_as_uint(f);
    u = (u + 0x7FFFu + ((u >> 16) & 1u)) >> 16;   // round-to-nearest-even
    return (short)u;
}
__device__ __forceinline__ float bf2f(short s) {
    return __uint_as_float(((unsigned)(unsigned short)s) << 16);
}

__device__ __forceinline__ void async_load16(const void* g, void* l) {
    __builtin_amdgcn_global_load_lds(
        (const __attribute__((address_space(1))) void*)g,
        (__attribute__((address_space(3))) void*)l, 16, 0, 0);
}

// ---------------- init ----------------
__global__ void vq_init_kernel(u64* __restrict__ packed, float* __restrict__ avg_num,
                               int* __restrict__ ncand, float* __restrict__ scal,
                               float* __restrict__ G, float* __restrict__ SVmom) {
    int i = blockIdx.x * 256 + threadIdx.x;
    if (i < T_TOK) packed[i] = ~0ull;
    if (i < NE)    avg_num[i] = 0.f;
    if (i < T_TOK) ncand[i] = 0;
    if (i < 8)     scal[i] = 0.f;
    if (i < 81920) G[i] = 0.f;          // G_ek(4096) G_eg(36864) G_zk(4096) G_zg(36864)
    if (i < 1032)  SVmom[i] = 0.f;      // S_z,V_z,S_e,V_e (4x256) + mom(8)
}

// ---------------- normalize codebooks -> enorm fp32, e2k/e2s, Es (split bf16, -2x) --------
__global__ void norm_codes_kernel(const float* __restrict__ wk, const float* __restrict__ wg,
                                  float* __restrict__ enorm, float* __restrict__ e2k,
                                  float* __restrict__ e2s, short* __restrict__ Es) {
    int n = blockIdx.x, c = threadIdx.x;
    int lane = c & 63, w = c >> 6;
    float x = (c < 64) ? wk[n * 64 + c] : wg[n * 192 + (c - 64)];
    float s = x * x;
#pragma unroll
    for (int m = 1; m < 64; m <<= 1) s += __shfl_xor(s, m, 64);
    __shared__ float ws4[4];
    if (lane == 0) ws4[w] = s;
    __syncthreads();
    float sk = ws4[0], sg = ws4[1] + ws4[2] + ws4[3];
    float nk = fmaxf(sqrtf(sk), 1e-12f), ng = fmaxf(sqrtf(sg), 1e-12f);
    float y = x / ((c < 64) ? nk : ng);
    enorm[(size_t)n * KD + c] = y;
    if (c == 0) {
        float ek2 = sk / (nk * nk), eg2 = sg / (ng * ng);
        e2k[n] = ek2; e2s[n] = ek2 + eg2;
    }
    short h = f2bf(y);          float hf = bf2f(h);
    short l = f2bf(y - hf);     float lf = bf2f(l);
    short sh = f2bf(-2.f * hf), sl = f2bf(-2.f * lf);   // exact scaling
    short* Er = Es + (size_t)n * K3;
    if (c < 64) { Er[c] = sh; Er[64 + c] = sl; Er[128 + c] = sh; }
    else { int cc = c - 64; Er[192 + cc] = sh; Er[384 + cc] = sl; Er[576 + cc] = sh; }
}

// ---------------- normalize z (NCHW->token) -> znorm fp32, z2k/z2s, Zs (split bf16) -------
__global__ void norm_z_kernel(const float* __restrict__ z, float* __restrict__ znorm,
                              float* __restrict__ z2k, float* __restrict__ z2s,
                              short* __restrict__ Zs) {
    int t = blockIdx.x, c = threadIdx.x;
    int lane = c & 63, w = c >> 6;
    int b = t >> 10, hw = t & 1023;
    float x = z[((size_t)b * 256 + c) * 1024 + hw];
    float s = x * x;
#pragma unroll
    for (int m = 1; m < 64; m <<= 1) s += __shfl_xor(s, m, 64);
    __shared__ float ws4[4];
    if (lane == 0) ws4[w] = s;
    __syncthreads();
    float sk = ws4[0], sg = ws4[1] + ws4[2] + ws4[3];
    float nk = fmaxf(sqrtf(sk), 1e-12f), ng = fmaxf(sqrtf(sg), 1e-12f);
    float y = x / ((c < 64) ? nk : ng);
    znorm[(size_t)t * KD + c] = y;
    if (c == 0) {
        float zk2 = sk / (nk * nk), zg2 = sg / (ng * ng);
        z2k[t] = zk2; z2s[t] = zk2 + zg2;
    }
    short h = f2bf(y);      float hf = bf2f(h);
    short l = f2bf(y - hf);
    short* Zr = Zs + (size_t)t * K3;
    if (c < 64) { Zr[c] = h; Zr[64 + c] = h; Zr[128 + c] = l; }
    else { int cc = c - 64; Zr[192 + cc] = h; Zr[384 + cc] = h; Zr[576 + cc] = l; }
}

// ---------------- column sums: S = sum_rows x, V = sum_rows w*x ----------------
__global__ void colsum_kernel(const float* __restrict__ znorm, const float* __restrict__ enorm,
                              const float* __restrict__ z2k, const float* __restrict__ z2s,
                              const float* __restrict__ e2k, const float* __restrict__ e2s,
                              float* __restrict__ SV) {
    int b = blockIdx.x, c = threadIdx.x;
    float S = 0.f, V = 0.f;
    if (b < 64) {                       // Z: 64 rows per block
        int r0 = b * 64;
        for (int r = 0; r < 64; ++r) {
            int t = r0 + r;
            float x = znorm[(size_t)t * KD + c];
            float w = (c < 64) ? z2k[t] : (z2s[t] - z2k[t]);
            S += x; V = fmaf(w, x, V);
        }
        atomicAdd(&SV[c], S); atomicAdd(&SV[256 + c], V);
    } else {                            // E: 128 rows per block
        int r0 = (b - 64) * 128;
        for (int r = 0; r < 128; ++r) {
            int n = r0 + r;
            float x = enorm[(size_t)n * KD + c];
            float w = (c < 64) ? e2k[n] : (e2s[n] - e2k[n]);
            S += x; V = fmaf(w, x, V);
        }
        atomicAdd(&SV[512 + c], S); atomicAdd(&SV[768 + c], V);
    }
}

// ---------------- scalar moments: mom[8] = {Sz2k,Sz2k2,Sz2g,Sz2g2,Se2k,Se2k2,Se2g,Se2g2} --
__global__ void moments_kernel(const float* __restrict__ z2k, const float* __restrict__ z2s,
                               const float* __restrict__ e2k, const float* __restrict__ e2s,
                               float* __restrict__ mom) {
    int b = blockIdx.x, tid = threadIdx.x;
    int n = (b == 0) ? T_TOK : NE;
    const float* ak = (b == 0) ? z2k : e2k;
    const float* as = (b == 0) ? z2s : e2s;
    float s0 = 0, s1 = 0, s2 = 0, s3 = 0;
    for (int i = tid; i < n; i += 256) {
        float a = ak[i], g = as[i] - a;
        s0 += a; s1 = fmaf(a, a, s1); s2 += g; s3 = fmaf(g, g, s3);
    }
    __shared__ float red[256];
    float* dst = mom + b * 4;
    float vals[4] = {s0, s1, s2, s3};
    for (int q = 0; q < 4; ++q) {
        red[tid] = vals[q]; __syncthreads();
        for (int st = 128; st > 0; st >>= 1) { if (tid < st) red[tid] += red[tid + st]; __syncthreads(); }
        if (tid == 0) dst[q] = red[0];
        __syncthreads();
    }
}

// ---------------- Gram matrices G = X^T X (diagonal parts only), fused 4 jobs ----------
// jobs: [0,32) E-k | [32,320) E-g | [320,328) Z-k | [328,400) Z-g
__global__ __launch_bounds__(256)
void gram_kernel(const float* __restrict__ znorm, const float* __restrict__ enorm,
                 float* __restrict__ Gbuf) {
    int b = blockIdx.x;
    const float* X; float* G; int nrows, c0, W, itiles, splitk, local;
    if (b < 32)       { X = enorm; G = Gbuf;         nrows = NE;    c0 = 0;  W = 64;  itiles = 2; splitk = 16; local = b; }
    else if (b < 320) { X = enorm; G = Gbuf + 4096;  nrows = NE;    c0 = 64; W = 192; itiles = 6; splitk = 16; local = b - 32; }
    else if (b < 328) { X = znorm; G = Gbuf + 40960; nrows = T_TOK; c0 = 0;  W = 64;  itiles = 2; splitk = 4;  local = b - 320; }
    else              { X = znorm; G = Gbuf + 45056; nrows = T_TOK; c0 = 64; W = 192; itiles = 6; splitk = 4;  local = b - 328; }
    int ks = local % splitk, rem = local / splitk;
    int i0 = (rem % itiles) * 32, j0 = (rem / itiles) * 64;
    int rows = nrows / splitk, r0 = ks * rows;

    __shared__ float xs[16 * 192];
    int tid = threadIdx.x;
    int ti = tid >> 5, tj = tid & 31;
    float acc[4][2] = {};
    for (int rb = 0; rb < rows; rb += 16) {
        __syncthreads();
        int nf4 = 4 * W;   // 16 rows * W/4 f4 per row
        for (int lin = tid; lin < nf4; lin += 256) {
            int r, f4;
            if (W == 64) { r = lin >> 4; f4 = lin & 15; } else { r = lin / 48; f4 = lin % 48; }
            *(float4*)&xs[r * W + f4 * 4] =
                *(const float4*)&X[(size_t)(r0 + rb + r) * KD + c0 + f4 * 4];
        }
        __syncthreads();
#pragma unroll 4
        for (int r = 0; r < 16; ++r) {
            float4 xi = *(const float4*)&xs[r * W + i0 + ti * 4];
            float xj0 = xs[r * W + j0 + tj * 2];
            float xj1 = xs[r * W + j0 + tj * 2 + 1];
#pragma unroll
            for (int a = 0; a < 4; ++a) {
                acc[a][0] = fmaf(xi[a], xj0, acc[a][0]);
                acc[a][1] = fmaf(xi[a], xj1, acc[a][1]);
            }
        }
    }
#pragma unroll
    for (int a = 0; a < 4; ++a) {
        int i = i0 + ti * 4 + a;
        atomicAdd(&G[i * W + j0 + tj * 2],     acc[a][0]);
        atomicAdd(&G[i * W + j0 + tj * 2 + 1], acc[a][1]);
    }
}

// ---------------- fused MFMA GEMM ----------------
// grid: x = token-block (32), y = code-block (128).
__global__ __launch_bounds__(256, 3)
void gemm_fused_kernel(const short* __restrict__ Zs, const short* __restrict__ Es,
                       const float* __restrict__ z2s, const float* __restrict__ e2s,
                       u64* __restrict__ packed, float* __restrict__ scal,
                       float* __restrict__ part_m, float* __restrict__ part_z,
                       float* __restrict__ part_w,
                       float* __restrict__ candD, int* __restrict__ candN,
                       int* __restrict__ ncand) {
    __shared__ __align__(16) short As[128 * 64];   // [token_row][k] 64 bf16/row
    __shared__ __align__(16) short Bs[128 * 64];   // [code_row][k]
    const int tid = threadIdx.x;
    const int lane = tid & 63, wid = tid >> 6;
    const int wm = wid >> 1, wn = wid & 1;         // wave tile: 64(tok) x 64(code)
    const int t0 = blockIdx.x * 128, n0 = blockIdx.y * 128;

    f32x4 acc[4][4];
#pragma unroll
    for (int bi = 0; bi < 4; ++bi)
#pragma unroll
        for (int bj = 0; bj < 4; ++bj) {
            f32x4 zz = {0.f, 0.f, 0.f, 0.f};
            acc[bi][bj] = zz;
        }

    auto stage = [&](int k0) {
        const int rb0 = wid * 32;
#pragma unroll
        for (int c2 = 0; c2 < 4; ++c2) {
            int rb = rb0 + c2 * 8;
            int row = rb + (lane >> 3);
            int q = (lane & 7) ^ (lane >> 3);   // XOR-quad swizzle (rb%8==0)
            async_load16(Zs + (size_t)(t0 + row) * K3 + k0 + q * 8, &As[rb * 64]);
            async_load16(Es + (size_t)(n0 + row) * K3 + k0 + q * 8, &Bs[rb * 64]);
        }
    };
    auto compute_half = [&](int s) {
        bf16x8 bfv[4];
#pragma unroll
        for (int bj = 0; bj < 4; ++bj) {
            int brow = wn * 64 + bj * 16 + (lane & 15);
            int q = ((s << 2) | (lane >> 4)) ^ (brow & 7);
            bfv[bj] = *reinterpret_cast<const bf16x8*>(&Bs[brow * 64 + q * 8]);
        }
#pragma unroll
        for (int bi = 0; bi < 4; ++bi) {
            int arow = wm * 64 + bi * 16 + (lane & 15);
            int q = ((s << 2) | (lane >> 4)) ^ (arow & 7);
            bf16x8 af = *reinterpret_cast<const bf16x8*>(&As[arow * 64 + q * 8]);
#pragma unroll
            for (int bj = 0; bj < 4; ++bj)
                acc[bi][bj] = __builtin_amdgcn_mfma_f32_16x16x32_bf16(
                    af, bfv[bj], acc[bi][bj], 0, 0, 0);
        }
    };

    int k0 = 0;
    for (int r = 0; r < 12; ++r) {             // acc = -2*(dot_k + dot_g)
        stage(k0); __syncthreads();
        compute_half(0); compute_half(1);
        __syncthreads(); k0 += 64;
    }

    // ---- epilogue ----
    char* lds = (char*)As;
    u64*   tokmin = (u64*)lds;                 // [128][2]   2048 B
    float* bmf    = (float*)(lds + 2048);      // [128]       512 B
    float* bthr   = (float*)(lds + 2560);      // [128]       512 B
    float* pzw    = (float*)(lds + 3072);      // [128][2][2] 2048 B

    float e2sv[4];
#pragma unroll
    for (int bj = 0; bj < 4; ++bj)
        e2sv[bj] = e2s[n0 + wn * 64 + bj * 16 + (lane & 15)];

    // pass 1: per-token wave-local packed min (d,n)
#pragma unroll
    for (int bi = 0; bi < 4; ++bi) {
        u64 pmin[4] = {~0ull, ~0ull, ~0ull, ~0ull};
        f32x4 z4 = *reinterpret_cast<const f32x4*>(
            &z2s[t0 + wm * 64 + bi * 16 + (lane >> 4) * 4]);
#pragma unroll
        for (int reg = 0; reg < 4; ++reg) {
#pragma unroll
            for (int bj = 0; bj < 4; ++bj) {
                float d = z4[reg] + e2sv[bj] + acc[bi][bj][reg];
                int n = n0 + wn * 64 + bj * 16 + (lane & 15);
                u64 pv = (((u64)__float_as_uint(d)) << 32) | (unsigned)n;
                if (pv < pmin[reg]) pmin[reg] = pv;
            }
        }
#pragma unroll
        for (int m = 1; m < 16; m <<= 1)
#pragma unroll
            for (int reg = 0; reg < 4; ++reg) {
                u64 o = __shfl_xor(pmin[reg], m, 64);
                if (o < pmin[reg]) pmin[reg] = o;
            }
        if ((lane & 15) == 0) {
#pragma unroll
            for (int reg = 0; reg < 4; ++reg) {
                int tl = wm * 64 + bi * 16 + (lane >> 4) * 4 + reg;
                tokmin[tl * 2 + wn] = pmin[reg];
            }
        }
    }
    __syncthreads();

    // owner step: block min -> global atomicMin (returns old => best-so-far)
    if (tid < 128) {
        int tl = tid;
        u64 bm = tokmin[tl * 2], b1 = tokmin[tl * 2 + 1];
        if (b1 < bm) bm = b1;
        u64 old = atomicMin(&packed[t0 + tl], bm);
        u64 gb = (old < bm) ? old : bm;
        float d_bmin = __uint_as_float((unsigned)(bm >> 32));
        bmf[tl] = -100.f * d_bmin;
        bthr[tl] = __uint_as_float((unsigned)(gb >> 32)) + DCUT;
    }
    __syncthreads();

    // pass 2: block-level softmax partials + candidate capture
#pragma unroll
    for (int bi = 0; bi < 4; ++bi) {
        float ez[4] = {0.f, 0.f, 0.f, 0.f}, ew[4] = {0.f, 0.f, 0.f, 0.f};
        f32x4 z4 = *reinterpret_cast<const f32x4*>(
            &z2s[t0 + wm * 64 + bi * 16 + (lane >> 4) * 4]);
#pragma unroll
        for (int reg = 0; reg < 4; ++reg) {
            int tl = wm * 64 + bi * 16 + (lane >> 4) * 4 + reg;
            int t = t0 + tl;
            float m_b = bmf[tl], thr = bthr[tl];
#pragma unroll
            for (int bj = 0; bj < 4; ++bj) {
                float d = z4[reg] + e2sv[bj] + acc[bi][bj][reg];
                float a = -100.f * d;
                float e = __expf(a - m_b);
                ez[reg] += e;
                ew[reg] = fmaf(a, e, ew[reg]);
                if (d <= thr) {
                    int pos = atomicAdd(&ncand[t], 1);
                    if (pos < CAP) {
                        candD[(size_t)t * CAP + pos] = d;
                        candN[(size_t)t * CAP + pos] = n0 + wn * 64 + bj * 16 + (lane & 15);
                    }
                }
            }
        }
#pragma unroll
        for (int m = 1; m < 16; m <<= 1)
#pragma unroll
            for (int reg = 0; reg < 4; ++reg) {
                ez[reg] += __shfl_xor(ez[reg], m, 64);
                ew[reg] += __shfl_xor(ew[reg], m, 64);
            }
        if ((lane & 15) == 0) {
#pragma unroll
            for (int reg = 0; reg < 4; ++reg) {
                int tl = wm * 64 + bi * 16 + (lane >> 4) * 4 + reg;
                pzw[(tl * 2 + wn) * 2 + 0] = ez[reg];
                pzw[(tl * 2 + wn) * 2 + 1] = ew[reg];
            }
        }
    }
    __syncthreads();

    // owner step 2: write per-block partials (coalesced)
    if (tid < 128) {
        int tl = tid;
        size_t o = (size_t)blockIdx.y * T_TOK + t0 + tl;
        part_m[o] = bmf[tl];
        part_z[o] = pzw[tl * 4 + 0] + pzw[tl * 4 + 2];
        part_w[o] = pzw[tl * 4 + 1] + pzw[tl * 4 + 3];
    }
}

// ---------------- combine: exact per-token softmax stats + idx unpack ----------------
__global__ void combine_kernel(const float* __restrict__ part_m, const float* __restrict__ part_z,
                               const float* __restrict__ part_w, const u64* __restrict__ packed,
                               float* __restrict__ m_arr, float* __restrict__ Z_arr,
                               int* __restrict__ idx_arr, float* __restrict__ out,
                               float* __restrict__ scal) {
    int lane = threadIdx.x;                 // 64
    int t = blockIdx.x * 64 + lane;
    float m = -3.0e38f, Z = 0.f, W = 0.f;
    for (int nb = 0; nb < NE / 128; ++nb) {
        size_t o = (size_t)nb * T_TOK + t;
        float mb = part_m[o], zb = part_z[o], wb = part_w[o];
        if (mb > m) { float s = __expf(m - mb); Z *= s; W *= s; m = mb; }
        float s2 = __expf(mb - m);
        Z = fmaf(zb, s2, Z); W = fmaf(wb, s2, W);
    }
    m_arr[t] = m; Z_arr[t] = Z;
    u64 pv = packed[t];
    int idx = (int)(pv & 0xFFFFFFFFull);
    idx_arr[t] = idx;
    out[1048581 + t] = (float)idx;
    float ent = m + logf(Z) - W / Z;        // -sum p log p for this token
#pragma unroll
    for (int mm = 1; mm < 64; mm <<= 1) ent += __shfl_xor(ent, mm, 64);
    if (lane == 0) atomicAdd(&scal[3], ent);
}

// ---------------- z_q gather + vq loss (LDS transpose, coalesced NCHW stores) --------
__global__ __launch_bounds__(256)
void zq_kernel(const float* __restrict__ enorm, const float* __restrict__ znorm,
               const int* __restrict__ idx_arr,
               float* __restrict__ out, float* __restrict__ scal) {
    __shared__ float q_lds[256][33];        // [c][token_local], padded
    __shared__ float red[256];
    int tid = threadIdx.x;
    int t0 = blockIdx.x * 32;               // 32 tokens per block, same b
    float sdq = 0.f;
    for (int tl = 0; tl < 32; ++tl) {
        int t = t0 + tl;
        float q = enorm[(size_t)idx_arr[t] * KD + tid];
        q_lds[tid][tl] = q;
        float zc = znorm[(size_t)t * KD + tid];
        float df = q - zc;
        sdq = fmaf(df, df, sdq);
    }
    __syncthreads();
    int b = t0 >> 10, hw0 = t0 & 1023;
    int cg = tid >> 5, hwl = tid & 31;
    for (int c0 = 0; c0 < 256; c0 += 8) {
        int c = c0 + cg;
        out[((size_t)(b * 256 + c)) * 1024 + hw0 + hwl] = q_lds[c][hwl];
    }
    red[tid] = sdq;
    __syncthreads();
    for (int s = 128; s > 0; s >>= 1) { if (tid < s) red[tid] += red[tid + s]; __syncthreads(); }
    if (tid == 0) atomicAdd(&scal[2], red[0]);
}

// ---------------- avg_probs scatter from candidates ----------------
__global__ void avg_scatter_kernel(const float* __restrict__ candD, const int* __restrict__ candN,
                                   const int* __restrict__ ncand, const float* __restrict__ m_arr,
                                   const float* __restrict__ Z_arr, float* __restrict__ avg_num) {
    int t = blockIdx.x, lane = threadIdx.x;  // 64
    int nc = min(ncand[t], CAP);
    float m = m_arr[t], Z = Z_arr[t];
    for (int i = lane; i < nc; i += 64) {
        float a = -100.f * candD[(size_t)t * CAP + i];
        atomicAdd(&avg_num[candN[(size_t)t * CAP + i]], __expf(a - m) / Z);
    }
}

// ---------------- final scalars (incl. closed-form d-norms) ----------------
__global__ void finalize_kernel(const float* __restrict__ avg_num, const float* __restrict__ scal,
                                const float* __restrict__ G, const float* __restrict__ SVmom,
                                float* __restrict__ out) {
    __shared__ float red[256];
    int tid = threadIdx.x;
    // avg_probs entropy
    float s = 0.f;
    for (int n = tid; n < NE; n += 256) {
        float avg = avg_num[n] * (1.f / 4096.f);
        s += avg * logf(avg + 1e-5f);
    }
    red[tid] = s; __syncthreads();
    for (int st = 128; st > 0; st >>= 1) { if (tid < st) red[tid] += red[tid + st]; __syncthreads(); }
    float avg_ent_neg = (tid == 0) ? red[0] : 0.f;
    __syncthreads();

    // closed-form d-norms: sum d^2 = term1 - 4*term2 + 4*term3
    const float* G_ek = G;
    const float* G_eg = G + 4096;
    const float* G_zk = G + 40960;
    const float* G_zg = G + 45056;
    float rk = 0.f, rg = 0.f;
    for (int i = tid; i < 4096; i += 256)  rk = fmaf(G_zk[i], G_ek[i], rk);
    for (int i = tid; i < 36864; i += 256) rg = fmaf(G_zg[i], G_eg[i], rg);
    {   // column term: V_z.S_e + S_z.V_e
        int c = tid;
        float v = SVmom[256 + c] * SVmom[512 + c] + SVmom[c] * SVmom[768 + c];
        if (c < 64) rk -= v; else rg -= v;
    }
    red[tid] = 4.f * rk; __syncthreads();
    for (int st = 128; st > 0; st >>= 1) { if (tid < st) red[tid] += red[tid + st]; __syncthreads(); }
    float red_k = red[0];
    __syncthreads();
    red[tid] = 4.f * rg; __syncthreads();
    for (int st = 128; st > 0; st >>= 1) { if (tid < st) red[tid] += red[tid + st]; __syncthreads(); }
    float red_g = red[0];

    if (tid == 0) {
        const float* mom = SVmom + 1024;
        float term1k = NE * mom[1] + 2.f * mom[0] * mom[4] + T_TOK * mom[5];
        float term1g = NE * mom[3] + 2.f * mom[2] * mom[6] + T_TOK * mom[7];
        float sdk2 = term1k + red_k;
        float sdg2 = term1g + red_g;
        float avg_ent = -avg_ent_neg;
        float se = scal[3] * (1.f / 4096.f);
        float vq = scal[2] * (1.f / 1048576.f);
        out[1048576] = vq;
        out[1048577] = 0.25f * vq;
        out[1048578] = 0.1f * (se - avg_ent);
        out[1048579] = sdk2 * (1.f / 4096.f);
        out[1048580] = sdg2 * (1.f / 4096.f);
    }
}

// ---------------- host ----------------
extern "C" void kernel_launch(void* const* d_in, const int* in_sizes, int n_in,
                              void* d_out, int out_size, void* d_ws, size_t ws_size,
                              hipStream_t stream) {
    const float* z  = (const float*)d_in[0];
    const float* wk = (const float*)d_in[1];
    const float* wg = (const float*)d_in[2];
    float* out = (float*)d_out;

    char* ws = (char*)d_ws;
    size_t off = 0;
    auto alloc = [&](size_t bytes) {
        void* p = ws + off;
        off += (bytes + 255) & ~(size_t)255;
        return p;
    };
    float* enorm  = (float*)alloc((size_t)NE * KD * 4);        // 16.78 MB
    float* znorm  = (float*)alloc((size_t)T_TOK * KD * 4);     //  4.19 MB
    short* Es     = (short*)alloc((size_t)NE * K3 * 2);        // 25.17 MB
    short* Zs     = (short*)alloc((size_t)T_TOK * K3 * 2);     //  6.29 MB
    float* e2k    = (float*)alloc(NE * 4);
    float* e2s    = (float*)alloc(NE * 4);
    float* z2k    = (float*)alloc(T_TOK * 4);
    float* z2s    = (float*)alloc(T_TOK * 4);
    u64*   packed = (u64*)alloc(T_TOK * 8);
    float* m_arr  = (float*)alloc(T_TOK * 4);
    float* Z_arr  = (float*)alloc(T_TOK * 4);
    int*   idx_arr= (int*)alloc(T_TOK * 4);
    int*   ncand  = (int*)alloc(T_TOK * 4);
    float* part_m = (float*)alloc((size_t)(NE / 128) * T_TOK * 4);  // 2.10 MB
    float* part_z = (float*)alloc((size_t)(NE / 128) * T_TOK * 4);  // 2.10 MB
    float* part_w = (float*)alloc((size_t)(NE / 128) * T_TOK * 4);  // 2.10 MB
    float* candD  = (float*)alloc((size_t)T_TOK * CAP * 4);    // 12.58 MB
    int*   candN  = (int*)alloc((size_t)T_TOK * CAP * 4);      // 12.58 MB
    float* avg_num= (float*)alloc(NE * 4);
    float* scal   = (float*)alloc(8 * 4);
    float* Gbuf   = (float*)alloc(81920 * 4);                  // Gram blocks, 328 KB
    float* SVmom  = (float*)alloc(1032 * 4);                   // S/V cols + moments

    vq_init_kernel<<<384, 256, 0, stream>>>(packed, avg_num, ncand, scal, Gbuf, SVmom);
    norm_codes_kernel<<<NE, 256, 0, stream>>>(wk, wg, enorm, e2k, e2s, Es);
    norm_z_kernel<<<T_TOK, 256, 0, stream>>>(z, znorm, z2k, z2s, Zs);

    colsum_kernel<<<192, 256, 0, stream>>>(znorm, enorm, z2k, z2s, e2k, e2s, SVmom);
    moments_kernel<<<2, 256, 0, stream>>>(z2k, z2s, e2k, e2s, SVmom + 1024);
    gram_kernel<<<400, 256, 0, stream>>>(znorm, enorm, Gbuf);

    dim3 gg(T_TOK / 128, NE / 128);   // x = token-block, y = code-block
    gemm_fused_kernel<<<gg, 256, 0, stream>>>(Zs, Es, z2s, e2s,
                                              packed, scal, part_m, part_z, part_w,
                                              candD, candN, ncand);
    combine_kernel<<<T_TOK / 64, 64, 0, stream>>>(part_m, part_z, part_w, packed,
                                                  m_arr, Z_arr, idx_arr, out, scal);
    zq_kernel<<<T_TOK / 32, 256, 0, stream>>>(enorm, znorm, idx_arr, out, scal);
    avg_scatter_kernel<<<T_TOK, 64, 0, stream>>>(candD, candN, ncand, m_arr, Z_arr, avg_num);
    finalize_kernel<<<1, 256, 0, stream>>>(avg_num, scal, Gbuf, SVmom, out);
}

// Round 7
// 470.706 us; speedup vs baseline: 1.0058x; 1.0058x over previous
//
#include <hip/hip_runtime.h>

// VectorQuantizer forward, MI355X. Split-bf16 MFMA GEMM (hi/lo, 3 products,
// K extended 256->768), single accumulator, occupancy 4 blocks/CU. Epilogue:
// argmin + per-block online-softmax partials (exact entropy) +
// racy-shrinking-threshold candidate capture. d^2-norm split in closed form
// (Gram + colsums + moments). R7: norm/colsum/moments fused into 2 coalesced
// tile kernels; combine 4x parallel. T=4096 tokens, NE=16384 codes.

#define T_TOK 4096
#define NE    16384
#define KD    256
#define K3    768          // 3x split-extended K
#define CAP   768          // candidate slots per token (avg_probs only)
#define DCUT  0.15f        // capture window above best-so-far global min

typedef __attribute__((ext_vector_type(8))) short bf16x8;
typedef __attribute__((ext_vector_type(4))) float f32x4;
typedef unsigned long long u64;

__device__ __forceinline__ short f2bf(float f) {
    unsigned u = __float_as_uint(f);
    u = (u + 0x7FFFu + ((u >> 16) & 1u)) >> 16;   // round-to-nearest-even
    return (short)u;
}
__device__ __forceinline__ float bf2f(short s) {
    return __uint_as_float(((unsigned)(unsigned short)s) << 16);
}

__device__ __forceinline__ void async_load16(const void* g, void* l) {
    __builtin_amdgcn_global_load_lds(
        (const __attribute__((address_space(1))) void*)g,
        (__attribute__((address_space(3))) void*)l, 16, 0, 0);
}

// ---------------- init ----------------
__global__ void vq_init_kernel(u64* __restrict__ packed, float* __restrict__ avg_num,
                               int* __restrict__ ncand, float* __restrict__ scal,
                               float* __restrict__ G, float* __restrict__ SVmom) {
    int i = blockIdx.x * 256 + threadIdx.x;
    if (i < T_TOK) packed[i] = ~0ull;
    if (i < NE)    avg_num[i] = 0.f;
    if (i < T_TOK) ncand[i] = 0;
    if (i < 8)     scal[i] = 0.f;
    if (i < 81920) G[i] = 0.f;          // G_ek(4096) G_eg(36864) G_zk(4096) G_zg(36864)
    if (i < 1032)  SVmom[i] = 0.f;      // S_z,V_z,S_e,V_e (4x256) + mom(8)
}

// ---------------- prep codes: normalize 64 rows/block + colsum + moments ----------------
__global__ __launch_bounds__(256)
void prep_codes_kernel(const float* __restrict__ wk, const float* __restrict__ wg,
                       float* __restrict__ enorm, float* __restrict__ e2k,
                       float* __restrict__ e2s, short* __restrict__ Es,
                       float* __restrict__ SV, float* __restrict__ mom) {
    __shared__ float xs[64][257];       // 65.8 KB, +1 pad
    __shared__ float ps[64][4];
    __shared__ float rnorm[64][2];      // 1/nk, 1/ng
    __shared__ float rw[64][2];         // e2k, e2g
    int tid = threadIdx.x;
    int n0 = blockIdx.x * 64;
    // coalesced loads (addr = base + linear idx)
    for (int i = 0; i < 16; ++i) {
        int idx = tid + i * 256;
        xs[idx >> 6][idx & 63] = wk[(size_t)n0 * 64 + idx];
    }
    for (int i = 0; i < 48; ++i) {
        int idx = tid + i * 256;
        xs[idx / 192][64 + idx % 192] = wg[(size_t)n0 * 192 + idx];
    }
    __syncthreads();
    // row partial sums of squares
    {
        int r = tid & 63, part = tid >> 6;
        float s = 0.f;
        for (int j = 0; j < 64; ++j) { float v = xs[r][part * 64 + j]; s = fmaf(v, v, s); }
        ps[r][part] = s;
    }
    __syncthreads();
    if (tid < 64) {
        float sk = ps[tid][0], sg = ps[tid][1] + ps[tid][2] + ps[tid][3];
        float nk = fmaxf(sqrtf(sk), 1e-12f), ng = fmaxf(sqrtf(sg), 1e-12f);
        float ek2 = sk / (nk * nk), eg2 = sg / (ng * ng);
        rnorm[tid][0] = 1.f / nk; rnorm[tid][1] = 1.f / ng;
        rw[tid][0] = ek2; rw[tid][1] = eg2;
        e2k[n0 + tid] = ek2; e2s[n0 + tid] = ek2 + eg2;
    }
    __syncthreads();
    // write enorm + Es, one row per step (coalesced)
    int c = tid;
    float rn = 0.f;  // placeholder
    for (int i = 0; i < 64; ++i) {
        float y = xs[i][c] * rnorm[i][(c < 64) ? 0 : 1];
        enorm[(size_t)(n0 + i) * KD + c] = y;
        short h = f2bf(y);          float hf = bf2f(h);
        short l = f2bf(y - hf);     float lf = bf2f(l);
        short sh = f2bf(-2.f * hf), sl = f2bf(-2.f * lf);
        short* Er = Es + (size_t)(n0 + i) * K3;
        if (c < 64) { Er[c] = sh; Er[64 + c] = sl; Er[128 + c] = sh; }
        else { int cc = c - 64; Er[192 + cc] = sh; Er[384 + cc] = sl; Er[576 + cc] = sh; }
    }
    (void)rn;
    // column sums over this block's 64 rows
    {
        int sel = (c < 64) ? 0 : 1;
        float S = 0.f, V = 0.f;
        for (int r = 0; r < 64; ++r) {
            float y = xs[r][c] * rnorm[r][sel];
            S += y; V = fmaf(rw[r][sel], y, V);
        }
        atomicAdd(&SV[512 + c], S); atomicAdd(&SV[768 + c], V);
    }
    // moments partials
    if (tid < 64) {
        float a = rw[tid][0], g = rw[tid][1];
        float s0 = a, s1 = a * a, s2 = g, s3 = g * g;
#pragma unroll
        for (int m = 1; m < 64; m <<= 1) {
            s0 += __shfl_xor(s0, m, 64); s1 += __shfl_xor(s1, m, 64);
            s2 += __shfl_xor(s2, m, 64); s3 += __shfl_xor(s3, m, 64);
        }
        if (tid == 0) {
            atomicAdd(&mom[4], s0); atomicAdd(&mom[5], s1);
            atomicAdd(&mom[6], s2); atomicAdd(&mom[7], s3);
        }
    }
}

// ---------------- prep z: NCHW->token transpose + normalize + colsum + moments ----------
__global__ __launch_bounds__(256)
void prep_z_kernel(const float* __restrict__ z, float* __restrict__ znorm,
                   float* __restrict__ z2k, float* __restrict__ z2s,
                   short* __restrict__ Zs, float* __restrict__ SV,
                   float* __restrict__ mom) {
    __shared__ float xs[64][257];
    __shared__ float ps[64][4];
    __shared__ float rnorm[64][2];
    __shared__ float rw[64][2];
    int tid = threadIdx.x;
    int b = blockIdx.x >> 4, hw0 = (blockIdx.x & 15) * 64;
    int t0 = b * 1024 + hw0;
    // coalesced load: consecutive tid -> consecutive hw within channel c
    for (int i = 0; i < 64; ++i) {
        int idx = tid + i * 256;
        int cc = idx >> 6, hwl = idx & 63;
        xs[hwl][cc] = z[((size_t)b * 256 + cc) * 1024 + hw0 + hwl];
    }
    __syncthreads();
    {
        int r = tid & 63, part = tid >> 6;
        float s = 0.f;
        for (int j = 0; j < 64; ++j) { float v = xs[r][part * 64 + j]; s = fmaf(v, v, s); }
        ps[r][part] = s;
    }
    __syncthreads();
    if (tid < 64) {
        float sk = ps[tid][0], sg = ps[tid][1] + ps[tid][2] + ps[tid][3];
        float nk = fmaxf(sqrtf(sk), 1e-12f), ng = fmaxf(sqrtf(sg), 1e-12f);
        float zk2 = sk / (nk * nk), zg2 = sg / (ng * ng);
        rnorm[tid][0] = 1.f / nk; rnorm[tid][1] = 1.f / ng;
        rw[tid][0] = zk2; rw[tid][1] = zg2;
        z2k[t0 + tid] = zk2; z2s[t0 + tid] = zk2 + zg2;
    }
    __syncthreads();
    int c = tid;
    for (int i = 0; i < 64; ++i) {
        float y = xs[i][c] * rnorm[i][(c < 64) ? 0 : 1];
        znorm[(size_t)(t0 + i) * KD + c] = y;
        short h = f2bf(y);      float hf = bf2f(h);
        short l = f2bf(y - hf);
        short* Zr = Zs + (size_t)(t0 + i) * K3;
        if (c < 64) { Zr[c] = h; Zr[64 + c] = h; Zr[128 + c] = l; }
        else { int cc = c - 64; Zr[192 + cc] = h; Zr[384 + cc] = h; Zr[576 + cc] = l; }
    }
    {
        int sel = (c < 64) ? 0 : 1;
        float S = 0.f, V = 0.f;
        for (int r = 0; r < 64; ++r) {
            float y = xs[r][c] * rnorm[r][sel];
            S += y; V = fmaf(rw[r][sel], y, V);
        }
        atomicAdd(&SV[c], S); atomicAdd(&SV[256 + c], V);
    }
    if (tid < 64) {
        float a = rw[tid][0], g = rw[tid][1];
        float s0 = a, s1 = a * a, s2 = g, s3 = g * g;
#pragma unroll
        for (int m = 1; m < 64; m <<= 1) {
            s0 += __shfl_xor(s0, m, 64); s1 += __shfl_xor(s1, m, 64);
            s2 += __shfl_xor(s2, m, 64); s3 += __shfl_xor(s3, m, 64);
        }
        if (tid == 0) {
            atomicAdd(&mom[0], s0); atomicAdd(&mom[1], s1);
            atomicAdd(&mom[2], s2); atomicAdd(&mom[3], s3);
        }
    }
}

// ---------------- Gram matrices G = X^T X (diagonal parts only), fused 4 jobs ----------
// jobs: [0,32) E-k | [32,320) E-g | [320,328) Z-k | [328,400) Z-g
__global__ __launch_bounds__(256)
void gram_kernel(const float* __restrict__ znorm, const float* __restrict__ enorm,
                 float* __restrict__ Gbuf) {
    int b = blockIdx.x;
    const float* X; float* G; int nrows, c0, W, itiles, splitk, local;
    if (b < 32)       { X = enorm; G = Gbuf;         nrows = NE;    c0 = 0;  W = 64;  itiles = 2; splitk = 16; local = b; }
    else if (b < 320) { X = enorm; G = Gbuf + 4096;  nrows = NE;    c0 = 64; W = 192; itiles = 6; splitk = 16; local = b - 32; }
    else if (b < 328) { X = znorm; G = Gbuf + 40960; nrows = T_TOK; c0 = 0;  W = 64;  itiles = 2; splitk = 4;  local = b - 320; }
    else              { X = znorm; G = Gbuf + 45056; nrows = T_TOK; c0 = 64; W = 192; itiles = 6; splitk = 4;  local = b - 328; }
    int ks = local % splitk, rem = local / splitk;
    int i0 = (rem % itiles) * 32, j0 = (rem / itiles) * 64;
    int rows = nrows / splitk, r0 = ks * rows;

    __shared__ float xs[16 * 192];
    int tid = threadIdx.x;
    int ti = tid >> 5, tj = tid & 31;
    float acc[4][2] = {};
    for (int rb = 0; rb < rows; rb += 16) {
        __syncthreads();
        int nf4 = 4 * W;
        for (int lin = tid; lin < nf4; lin += 256) {
            int r, f4;
            if (W == 64) { r = lin >> 4; f4 = lin & 15; } else { r = lin / 48; f4 = lin % 48; }
            *(float4*)&xs[r * W + f4 * 4] =
                *(const float4*)&X[(size_t)(r0 + rb + r) * KD + c0 + f4 * 4];
        }
        __syncthreads();
#pragma unroll 4
        for (int r = 0; r < 16; ++r) {
            float4 xi = *(const float4*)&xs[r * W + i0 + ti * 4];
            float xj0 = xs[r * W + j0 + tj * 2];
            float xj1 = xs[r * W + j0 + tj * 2 + 1];
#pragma unroll
            for (int a = 0; a < 4; ++a) {
                acc[a][0] = fmaf(xi[a], xj0, acc[a][0]);
                acc[a][1] = fmaf(xi[a], xj1, acc[a][1]);
            }
        }
    }
#pragma unroll
    for (int a = 0; a < 4; ++a) {
        int i = i0 + ti * 4 + a;
        atomicAdd(&G[i * W + j0 + tj * 2],     acc[a][0]);
        atomicAdd(&G[i * W + j0 + tj * 2 + 1], acc[a][1]);
    }
}

// ---------------- fused MFMA GEMM ----------------
// grid: x = token-block (32), y = code-block (128).
__global__ __launch_bounds__(256, 4)
void gemm_fused_kernel(const short* __restrict__ Zs, const short* __restrict__ Es,
                       const float* __restrict__ z2s, const float* __restrict__ e2s,
                       u64* __restrict__ packed, float* __restrict__ scal,
                       float* __restrict__ part_m, float* __restrict__ part_z,
                       float* __restrict__ part_w,
                       float* __restrict__ candD, int* __restrict__ candN,
                       int* __restrict__ ncand) {
    __shared__ __align__(16) short As[128 * 64];   // [token_row][k] 64 bf16/row
    __shared__ __align__(16) short Bs[128 * 64];   // [code_row][k]
    const int tid = threadIdx.x;
    const int lane = tid & 63, wid = tid >> 6;
    const int wm = wid >> 1, wn = wid & 1;         // wave tile: 64(tok) x 64(code)
    const int t0 = blockIdx.x * 128, n0 = blockIdx.y * 128;

    f32x4 acc[4][4];
#pragma unroll
    for (int bi = 0; bi < 4; ++bi)
#pragma unroll
        for (int bj = 0; bj < 4; ++bj) {
            f32x4 zz = {0.f, 0.f, 0.f, 0.f};
            acc[bi][bj] = zz;
        }

    auto stage = [&](int k0) {
        const int rb0 = wid * 32;
#pragma unroll
        for (int c2 = 0; c2 < 4; ++c2) {
            int rb = rb0 + c2 * 8;
            int row = rb + (lane >> 3);
            int q = (lane & 7) ^ (lane >> 3);   // XOR-quad swizzle (rb%8==0)
            async_load16(Zs + (size_t)(t0 + row) * K3 + k0 + q * 8, &As[rb * 64]);
            async_load16(Es + (size_t)(n0 + row) * K3 + k0 + q * 8, &Bs[rb * 64]);
        }
    };
    auto compute_half = [&](int s) {
        bf16x8 bfv[4];
#pragma unroll
        for (int bj = 0; bj < 4; ++bj) {
            int brow = wn * 64 + bj * 16 + (lane & 15);
            int q = ((s << 2) | (lane >> 4)) ^ (brow & 7);
            bfv[bj] = *reinterpret_cast<const bf16x8*>(&Bs[brow * 64 + q * 8]);
        }
#pragma unroll
        for (int bi = 0; bi < 4; ++bi) {
            int arow = wm * 64 + bi * 16 + (lane & 15);
            int q = ((s << 2) | (lane >> 4)) ^ (arow & 7);
            bf16x8 af = *reinterpret_cast<const bf16x8*>(&As[arow * 64 + q * 8]);
#pragma unroll
            for (int bj = 0; bj < 4; ++bj)
                acc[bi][bj] = __builtin_amdgcn_mfma_f32_16x16x32_bf16(
                    af, bfv[bj], acc[bi][bj], 0, 0, 0);
        }
    };

    int k0 = 0;
    for (int r = 0; r < 12; ++r) {             // acc = -2*(dot_k + dot_g)
        stage(k0); __syncthreads();
        compute_half(0); compute_half(1);
        __syncthreads(); k0 += 64;
    }

    // ---- epilogue ----
    char* lds = (char*)As;
    u64*   tokmin = (u64*)lds;                 // [128][2]   2048 B
    float* bmf    = (float*)(lds + 2048);      // [128]       512 B
    float* bthr   = (float*)(lds + 2560);      // [128]       512 B
    float* pzw    = (float*)(lds + 3072);      // [128][2][2] 2048 B

    float e2sv[4];
#pragma unroll
    for (int bj = 0; bj < 4; ++bj)
        e2sv[bj] = e2s[n0 + wn * 64 + bj * 16 + (lane & 15)];

    // pass 1: per-token wave-local packed min (d,n)
#pragma unroll
    for (int bi = 0; bi < 4; ++bi) {
        u64 pmin[4] = {~0ull, ~0ull, ~0ull, ~0ull};
        f32x4 z4 = *reinterpret_cast<const f32x4*>(
            &z2s[t0 + wm * 64 + bi * 16 + (lane >> 4) * 4]);
#pragma unroll
        for (int reg = 0; reg < 4; ++reg) {
#pragma unroll
            for (int bj = 0; bj < 4; ++bj) {
                float d = z4[reg] + e2sv[bj] + acc[bi][bj][reg];
                int n = n0 + wn * 64 + bj * 16 + (lane & 15);
                u64 pv = (((u64)__float_as_uint(d)) << 32) | (unsigned)n;
                if (pv < pmin[reg]) pmin[reg] = pv;
            }
        }
#pragma unroll
        for (int m = 1; m < 16; m <<= 1)
#pragma unroll
            for (int reg = 0; reg < 4; ++reg) {
                u64 o = __shfl_xor(pmin[reg], m, 64);
                if (o < pmin[reg]) pmin[reg] = o;
            }
        if ((lane & 15) == 0) {
#pragma unroll
            for (int reg = 0; reg < 4; ++reg) {
                int tl = wm * 64 + bi * 16 + (lane >> 4) * 4 + reg;
                tokmin[tl * 2 + wn] = pmin[reg];
            }
        }
    }
    __syncthreads();

    // owner step: block min -> global atomicMin (returns old => best-so-far)
    if (tid < 128) {
        int tl = tid;
        u64 bm = tokmin[tl * 2], b1 = tokmin[tl * 2 + 1];
        if (b1 < bm) bm = b1;
        u64 old = atomicMin(&packed[t0 + tl], bm);
        u64 gb = (old < bm) ? old : bm;
        float d_bmin = __uint_as_float((unsigned)(bm >> 32));
        bmf[tl] = -100.f * d_bmin;
        bthr[tl] = __uint_as_float((unsigned)(gb >> 32)) + DCUT;
    }
    __syncthreads();

    // pass 2: block-level softmax partials + candidate capture
#pragma unroll
    for (int bi = 0; bi < 4; ++bi) {
        float ez[4] = {0.f, 0.f, 0.f, 0.f}, ew[4] = {0.f, 0.f, 0.f, 0.f};
        f32x4 z4 = *reinterpret_cast<const f32x4*>(
            &z2s[t0 + wm * 64 + bi * 16 + (lane >> 4) * 4]);
#pragma unroll
        for (int reg = 0; reg < 4; ++reg) {
            int tl = wm * 64 + bi * 16 + (lane >> 4) * 4 + reg;
            int t = t0 + tl;
            float m_b = bmf[tl], thr = bthr[tl];
#pragma unroll
            for (int bj = 0; bj < 4; ++bj) {
                float d = z4[reg] + e2sv[bj] + acc[bi][bj][reg];
                float a = -100.f * d;
                float e = __expf(a - m_b);
                ez[reg] += e;
                ew[reg] = fmaf(a, e, ew[reg]);
                if (d <= thr) {
                    int pos = atomicAdd(&ncand[t], 1);
                    if (pos < CAP) {
                        candD[(size_t)t * CAP + pos] = d;
                        candN[(size_t)t * CAP + pos] = n0 + wn * 64 + bj * 16 + (lane & 15);
                    }
                }
            }
        }
#pragma unroll
        for (int m = 1; m < 16; m <<= 1)
#pragma unroll
            for (int reg = 0; reg < 4; ++reg) {
                ez[reg] += __shfl_xor(ez[reg], m, 64);
                ew[reg] += __shfl_xor(ew[reg], m, 64);
            }
        if ((lane & 15) == 0) {
#pragma unroll
            for (int reg = 0; reg < 4; ++reg) {
                int tl = wm * 64 + bi * 16 + (lane >> 4) * 4 + reg;
                pzw[(tl * 2 + wn) * 2 + 0] = ez[reg];
                pzw[(tl * 2 + wn) * 2 + 1] = ew[reg];
            }
        }
    }
    __syncthreads();

    // owner step 2: write per-block partials (coalesced)
    if (tid < 128) {
        int tl = tid;
        size_t o = (size_t)blockIdx.y * T_TOK + t0 + tl;
        part_m[o] = bmf[tl];
        part_z[o] = pzw[tl * 4 + 0] + pzw[tl * 4 + 2];
        part_w[o] = pzw[tl * 4 + 1] + pzw[tl * 4 + 3];
    }
}

// ---------------- combine: exact per-token softmax stats + idx unpack (4x parallel) -----
__global__ __launch_bounds__(256)
void combine_kernel(const float* __restrict__ part_m, const float* __restrict__ part_z,
                    const float* __restrict__ part_w, const u64* __restrict__ packed,
                    float* __restrict__ m_arr, float* __restrict__ Z_arr,
                    int* __restrict__ idx_arr, float* __restrict__ out,
                    float* __restrict__ scal) {
    __shared__ float sm[64][4], sz[64][4], sw[64][4];
    int tid = threadIdx.x, tl = tid & 63, q = tid >> 6;
    int t = blockIdx.x * 64 + tl;
    float m = -3.0e38f, Z = 0.f, W = 0.f;
    for (int nb = q * 32; nb < q * 32 + 32; ++nb) {
        size_t o = (size_t)nb * T_TOK + t;
        float mb = part_m[o], zb = part_z[o], wb = part_w[o];
        if (mb > m) { float s = __expf(m - mb); Z *= s; W *= s; m = mb; }
        float s2 = __expf(mb - m);
        Z = fmaf(zb, s2, Z); W = fmaf(wb, s2, W);
    }
    sm[tl][q] = m; sz[tl][q] = Z; sw[tl][q] = W;
    __syncthreads();
    if (tid < 64) {
        float M = sm[tid][0], Zt = sz[tid][0], Wt = sw[tid][0];
#pragma unroll
        for (int qq = 1; qq < 4; ++qq) {
            float mb = sm[tid][qq], Zb = sz[tid][qq], Wb = sw[tid][qq];
            if (mb > M) { float s = __expf(M - mb); Zt *= s; Wt *= s; M = mb; }
            float s2 = __expf(mb - M);
            Zt = fmaf(Zb, s2, Zt); Wt = fmaf(Wb, s2, Wt);
        }
        int tt = blockIdx.x * 64 + tid;
        m_arr[tt] = M; Z_arr[tt] = Zt;
        u64 pv = packed[tt];
        int idx = (int)(pv & 0xFFFFFFFFull);
        idx_arr[tt] = idx;
        out[1048581 + tt] = (float)idx;
        float ent = M + logf(Zt) - Wt / Zt;
#pragma unroll
        for (int mm = 1; mm < 64; mm <<= 1) ent += __shfl_xor(ent, mm, 64);
        if (tid == 0) atomicAdd(&scal[3], ent);
    }
}

// ---------------- z_q gather + vq loss (LDS transpose, coalesced NCHW stores) --------
__global__ __launch_bounds__(256)
void zq_kernel(const float* __restrict__ enorm, const float* __restrict__ znorm,
               const int* __restrict__ idx_arr,
               float* __restrict__ out, float* __restrict__ scal) {
    __shared__ float q_lds[256][33];        // [c][token_local], padded
    __shared__ float red[256];
    int tid = threadIdx.x;
    int t0 = blockIdx.x * 32;               // 32 tokens per block, same b
    float sdq = 0.f;
    for (int tl = 0; tl < 32; ++tl) {
        int t = t0 + tl;
        float q = enorm[(size_t)idx_arr[t] * KD + tid];
        q_lds[tid][tl] = q;
        float zc = znorm[(size_t)t * KD + tid];
        float df = q - zc;
        sdq = fmaf(df, df, sdq);
    }
    __syncthreads();
    int b = t0 >> 10, hw0 = t0 & 1023;
    int cg = tid >> 5, hwl = tid & 31;
    for (int c0 = 0; c0 < 256; c0 += 8) {
        int c = c0 + cg;
        out[((size_t)(b * 256 + c)) * 1024 + hw0 + hwl] = q_lds[c][hwl];
    }
    red[tid] = sdq;
    __syncthreads();
    for (int s = 128; s > 0; s >>= 1) { if (tid < s) red[tid] += red[tid + s]; __syncthreads(); }
    if (tid == 0) atomicAdd(&scal[2], red[0]);
}

// ---------------- avg_probs scatter from candidates ----------------
__global__ void avg_scatter_kernel(const float* __restrict__ candD, const int* __restrict__ candN,
                                   const int* __restrict__ ncand, const float* __restrict__ m_arr,
                                   const float* __restrict__ Z_arr, float* __restrict__ avg_num) {
    int t = blockIdx.x, lane = threadIdx.x;  // 64
    int nc = min(ncand[t], CAP);
    float m = m_arr[t], Z = Z_arr[t];
    for (int i = lane; i < nc; i += 64) {
        float a = -100.f * candD[(size_t)t * CAP + i];
        atomicAdd(&avg_num[candN[(size_t)t * CAP + i]], __expf(a - m) / Z);
    }
}

// ---------------- final scalars (incl. closed-form d-norms) ----------------
__global__ void finalize_kernel(const float* __restrict__ avg_num, const float* __restrict__ scal,
                                const float* __restrict__ G, const float* __restrict__ SVmom,
                                float* __restrict__ out) {
    __shared__ float red[256];
    int tid = threadIdx.x;
    float s = 0.f;
    for (int n = tid; n < NE; n += 256) {
        float avg = avg_num[n] * (1.f / 4096.f);
        s += avg * logf(avg + 1e-5f);
    }
    red[tid] = s; __syncthreads();
    for (int st = 128; st > 0; st >>= 1) { if (tid < st) red[tid] += red[tid + st]; __syncthreads(); }
    float avg_ent_neg = (tid == 0) ? red[0] : 0.f;
    __syncthreads();

    const float* G_ek = G;
    const float* G_eg = G + 4096;
    const float* G_zk = G + 40960;
    const float* G_zg = G + 45056;
    float rk = 0.f, rg = 0.f;
    for (int i = tid; i < 4096; i += 256)  rk = fmaf(G_zk[i], G_ek[i], rk);
    for (int i = tid; i < 36864; i += 256) rg = fmaf(G_zg[i], G_eg[i], rg);
    {
        int c = tid;
        float v = SVmom[256 + c] * SVmom[512 + c] + SVmom[c] * SVmom[768 + c];
        if (c < 64) rk -= v; else rg -= v;
    }
    red[tid] = 4.f * rk; __syncthreads();
    for (int st = 128; st > 0; st >>= 1) { if (tid < st) red[tid] += red[tid + st]; __syncthreads(); }
    float red_k = red[0];
    __syncthreads();
    red[tid] = 4.f * rg; __syncthreads();
    for (int st = 128; st > 0; st >>= 1) { if (tid < st) red[tid] += red[tid + st]; __syncthreads(); }
    float red_g = red[0];

    if (tid == 0) {
        const float* mom = SVmom + 1024;
        float term1k = NE * mom[1] + 2.f * mom[0] * mom[4] + T_TOK * mom[5];
        float term1g = NE * mom[3] + 2.f * mom[2] * mom[6] + T_TOK * mom[7];
        float sdk2 = term1k + red_k;
        float sdg2 = term1g + red_g;
        float avg_ent = -avg_ent_neg;
        float se = scal[3] * (1.f / 4096.f);
        float vq = scal[2] * (1.f / 1048576.f);
        out[1048576] = vq;
        out[1048577] = 0.25f * vq;
        out[1048578] = 0.1f * (se - avg_ent);
        out[1048579] = sdk2 * (1.f / 4096.f);
        out[1048580] = sdg2 * (1.f / 4096.f);
    }
}

// ---------------- host ----------------
extern "C" void kernel_launch(void* const* d_in, const int* in_sizes, int n_in,
                              void* d_out, int out_size, void* d_ws, size_t ws_size,
                              hipStream_t stream) {
    const float* z  = (const float*)d_in[0];
    const float* wk = (const float*)d_in[1];
    const float* wg = (const float*)d_in[2];
    float* out = (float*)d_out;

    char* ws = (char*)d_ws;
    size_t off = 0;
    auto alloc = [&](size_t bytes) {
        void* p = ws + off;
        off += (bytes + 255) & ~(size_t)255;
        return p;
    };
    float* enorm  = (float*)alloc((size_t)NE * KD * 4);        // 16.78 MB
    float* znorm  = (float*)alloc((size_t)T_TOK * KD * 4);     //  4.19 MB
    short* Es     = (short*)alloc((size_t)NE * K3 * 2);        // 25.17 MB
    short* Zs     = (short*)alloc((size_t)T_TOK * K3 * 2);     //  6.29 MB
    float* e2k    = (float*)alloc(NE * 4);
    float* e2s    = (float*)alloc(NE * 4);
    float* z2k    = (float*)alloc(T_TOK * 4);
    float* z2s    = (float*)alloc(T_TOK * 4);
    u64*   packed = (u64*)alloc(T_TOK * 8);
    float* m_arr  = (float*)alloc(T_TOK * 4);
    float* Z_arr  = (float*)alloc(T_TOK * 4);
    int*   idx_arr= (int*)alloc(T_TOK * 4);
    int*   ncand  = (int*)alloc(T_TOK * 4);
    float* part_m = (float*)alloc((size_t)(NE / 128) * T_TOK * 4);  // 2.10 MB
    float* part_z = (float*)alloc((size_t)(NE / 128) * T_TOK * 4);  // 2.10 MB
    float* part_w = (float*)alloc((size_t)(NE / 128) * T_TOK * 4);  // 2.10 MB
    float* candD  = (float*)alloc((size_t)T_TOK * CAP * 4);    // 12.58 MB
    int*   candN  = (int*)alloc((size_t)T_TOK * CAP * 4);      // 12.58 MB
    float* avg_num= (float*)alloc(NE * 4);
    float* scal   = (float*)alloc(8 * 4);
    float* Gbuf   = (float*)alloc(81920 * 4);                  // Gram blocks
    float* SVmom  = (float*)alloc(1032 * 4);                   // S/V cols + moments

    vq_init_kernel<<<384, 256, 0, stream>>>(packed, avg_num, ncand, scal, Gbuf, SVmom);
    prep_codes_kernel<<<NE / 64, 256, 0, stream>>>(wk, wg, enorm, e2k, e2s, Es,
                                                   SVmom, SVmom + 1024);
    prep_z_kernel<<<T_TOK / 64, 256, 0, stream>>>(z, znorm, z2k, z2s, Zs,
                                                  SVmom, SVmom + 1024);
    gram_kernel<<<400, 256, 0, stream>>>(znorm, enorm, Gbuf);

    dim3 gg(T_TOK / 128, NE / 128);   // x = token-block, y = code-block
    gemm_fused_kernel<<<gg, 256, 0, stream>>>(Zs, Es, z2s, e2s,
                                              packed, scal, part_m, part_z, part_w,
                                              candD, candN, ncand);
    combine_kernel<<<T_TOK / 64, 256, 0, stream>>>(part_m, part_z, part_w, packed,
                                                   m_arr, Z_arr, idx_arr, out, scal);
    zq_kernel<<<T_TOK / 32, 256, 0, stream>>>(enorm, znorm, idx_arr, out, scal);
    avg_scatter_kernel<<<T_TOK, 64, 0, stream>>>(candD, candN, ncand, m_arr, Z_arr, avg_num);
    finalize_kernel<<<1, 256, 0, stream>>>(avg_num, scal, Gbuf, SVmom, out);
}

// Round 8
// 438.706 us; speedup vs baseline: 1.0791x; 1.0729x over previous
//
#include <hip/hip_runtime.h>

// VectorQuantizer forward, MI355X. Split-bf16 MFMA GEMM (hi/lo, 3 products,
// K extended 256->768). Epilogue: argmin + per-block online-softmax partials
// (exact entropy) + racy-shrinking-threshold candidate capture. d^2-norm split
// in closed form (Gram + colsums + moments). R8: contended SV/mom atomics ->
// per-block partials + reduce; init folded into megaprep; combine+zq fused.
// 6 kernels total. T=4096 tokens, NE=16384 codes.

#define T_TOK 4096
#define NE    16384
#define KD    256
#define K3    768          // 3x split-extended K
#define CAP   768          // candidate slots per token (avg_probs only)
#define DCUT  0.15f        // capture window above best-so-far global min

#define NCB   512          // code prep blocks (32 rows each)
#define NZB   128          // z prep blocks (32 rows each)

typedef __attribute__((ext_vector_type(8))) short bf16x8;
typedef __attribute__((ext_vector_type(4))) float f32x4;
typedef unsigned long long u64;

__device__ __forceinline__ short f2bf(float f) {
    unsigned u = __float_as_uint(f);
    u = (u + 0x7FFFu + ((u >> 16) & 1u)) >> 16;   // round-to-nearest-even
    return (short)u;
}
__device__ __forceinline__ float bf2f(short s) {
    return __uint_as_float(((unsigned)(unsigned short)s) << 16);
}

__device__ __forceinline__ void async_load16(const void* g, void* l) {
    __builtin_amdgcn_global_load_lds(
        (const __attribute__((address_space(1))) void*)g,
        (__attribute__((address_space(3))) void*)l, 16, 0, 0);
}

// ---------------- megaprep: codes | z | init, branch on blockIdx ----------------
// blocks [0,NCB): codes, 32 rows each. [NCB,NCB+NZB): z, 32 tokens each.
// [NCB+NZB, +8): zero packed/avg_num/ncand/scal/G.
__global__ __launch_bounds__(256)
void megaprep_kernel(const float* __restrict__ wk, const float* __restrict__ wg,
                     const float* __restrict__ z,
                     float* __restrict__ enorm, float* __restrict__ e2k,
                     float* __restrict__ e2s, short* __restrict__ Es,
                     float* __restrict__ znorm, float* __restrict__ z2k,
                     float* __restrict__ z2s, short* __restrict__ Zs,
                     float* __restrict__ SVeS, float* __restrict__ SVeV,
                     float* __restrict__ SVzS, float* __restrict__ SVzV,
                     float* __restrict__ mompart,
                     u64* __restrict__ packed, float* __restrict__ avg_num,
                     int* __restrict__ ncand, float* __restrict__ scal,
                     float* __restrict__ G) {
    int b = blockIdx.x, tid = threadIdx.x;
    if (b >= NCB + NZB) {                    // ---- init branch ----
        int gid = (b - NCB - NZB) * 256 + tid;
        for (int i = gid; i < 81920; i += 2048) G[i] = 0.f;
        for (int i = gid; i < NE; i += 2048) avg_num[i] = 0.f;
        for (int i = gid; i < T_TOK; i += 2048) { packed[i] = ~0ull; ncand[i] = 0; }
        if (gid < 8) scal[gid] = 0.f;
        return;
    }

    __shared__ float xs[32][257];            // 32.9 KB
    __shared__ float ps[32][8];
    __shared__ float rnorm[32][2];
    __shared__ float rw[32][2];

    if (b < NCB) {                           // ---- codes branch ----
        int n0 = b * 32;
#pragma unroll
        for (int i = 0; i < 8; ++i) {        // wk: 32x64
            int idx = tid + i * 256;
            xs[idx >> 6][idx & 63] = wk[(size_t)n0 * 64 + idx];
        }
#pragma unroll
        for (int i = 0; i < 24; ++i) {       // wg: 32x192
            int idx = tid + i * 256;
            xs[idx / 192][64 + idx % 192] = wg[(size_t)n0 * 192 + idx];
        }
        __syncthreads();
        {
            int r = tid & 31, part = tid >> 5;
            float s = 0.f;
            for (int j = 0; j < 32; ++j) { float v = xs[r][part * 32 + j]; s = fmaf(v, v, s); }
            ps[r][part] = s;
        }
        __syncthreads();
        if (tid < 32) {
            float sk = ps[tid][0] + ps[tid][1];
            float sg = ps[tid][2] + ps[tid][3] + ps[tid][4] + ps[tid][5] + ps[tid][6] + ps[tid][7];
            float nk = fmaxf(sqrtf(sk), 1e-12f), ng = fmaxf(sqrtf(sg), 1e-12f);
            float ek2 = sk / (nk * nk), eg2 = sg / (ng * ng);
            rnorm[tid][0] = 1.f / nk; rnorm[tid][1] = 1.f / ng;
            rw[tid][0] = ek2; rw[tid][1] = eg2;
            e2k[n0 + tid] = ek2; e2s[n0 + tid] = ek2 + eg2;
        }
        __syncthreads();
        int c = tid;
        for (int i = 0; i < 32; ++i) {
            float y = xs[i][c] * rnorm[i][(c < 64) ? 0 : 1];
            enorm[(size_t)(n0 + i) * KD + c] = y;
            short h = f2bf(y);          float hf = bf2f(h);
            short l = f2bf(y - hf);
            short sh = f2bf(-2.f * hf), sl = f2bf(-2.f * bf2f(l));
            short* Er = Es + (size_t)(n0 + i) * K3;
            if (c < 64) { Er[c] = sh; Er[64 + c] = sl; Er[128 + c] = sh; }
            else { int cc = c - 64; Er[192 + cc] = sh; Er[384 + cc] = sl; Er[576 + cc] = sh; }
        }
        {   // column-sum partials (private slots, no atomics)
            int sel = (c < 64) ? 0 : 1;
            float S = 0.f, V = 0.f;
            for (int r = 0; r < 32; ++r) {
                float y = xs[r][c] * rnorm[r][sel];
                S += y; V = fmaf(rw[r][sel], y, V);
            }
            SVeS[(size_t)b * 256 + c] = S;
            SVeV[(size_t)b * 256 + c] = V;
        }
        if (tid < 32) {
            float a = rw[tid][0], g = rw[tid][1];
            float s0 = a, s1 = a * a, s2 = g, s3 = g * g;
#pragma unroll
            for (int m = 1; m < 32; m <<= 1) {
                s0 += __shfl_xor(s0, m, 64); s1 += __shfl_xor(s1, m, 64);
                s2 += __shfl_xor(s2, m, 64); s3 += __shfl_xor(s3, m, 64);
            }
            if (tid == 0) {
                mompart[b * 4 + 0] = s0; mompart[b * 4 + 1] = s1;
                mompart[b * 4 + 2] = s2; mompart[b * 4 + 3] = s3;
            }
        }
    } else {                                 // ---- z branch ----
        int jz = b - NCB;
        int t0 = jz * 32;
        int bb = t0 >> 10, hw0 = t0 & 1023;
#pragma unroll
        for (int i = 0; i < 32; ++i) {       // 32 tokens x 256 ch, transposed load
            int idx = tid + i * 256;
            int cc = idx >> 5, hwl = idx & 31;
            xs[hwl][cc] = z[(((size_t)bb * 256 + cc) << 10) + hw0 + hwl];
        }
        __syncthreads();
        {
            int r = tid & 31, part = tid >> 5;
            float s = 0.f;
            for (int j = 0; j < 32; ++j) { float v = xs[r][part * 32 + j]; s = fmaf(v, v, s); }
            ps[r][part] = s;
        }
        __syncthreads();
        if (tid < 32) {
            float sk = ps[tid][0] + ps[tid][1];
            float sg = ps[tid][2] + ps[tid][3] + ps[tid][4] + ps[tid][5] + ps[tid][6] + ps[tid][7];
            float nk = fmaxf(sqrtf(sk), 1e-12f), ng = fmaxf(sqrtf(sg), 1e-12f);
            float zk2 = sk / (nk * nk), zg2 = sg / (ng * ng);
            rnorm[tid][0] = 1.f / nk; rnorm[tid][1] = 1.f / ng;
            rw[tid][0] = zk2; rw[tid][1] = zg2;
            z2k[t0 + tid] = zk2; z2s[t0 + tid] = zk2 + zg2;
        }
        __syncthreads();
        int c = tid;
        for (int i = 0; i < 32; ++i) {
            float y = xs[i][c] * rnorm[i][(c < 64) ? 0 : 1];
            znorm[(size_t)(t0 + i) * KD + c] = y;
            short h = f2bf(y);      float hf = bf2f(h);
            short l = f2bf(y - hf);
            short* Zr = Zs + (size_t)(t0 + i) * K3;
            if (c < 64) { Zr[c] = h; Zr[64 + c] = h; Zr[128 + c] = l; }
            else { int cc = c - 64; Zr[192 + cc] = h; Zr[384 + cc] = h; Zr[576 + cc] = l; }
        }
        {
            int sel = (c < 64) ? 0 : 1;
            float S = 0.f, V = 0.f;
            for (int r = 0; r < 32; ++r) {
                float y = xs[r][c] * rnorm[r][sel];
                S += y; V = fmaf(rw[r][sel], y, V);
            }
            SVzS[(size_t)jz * 256 + c] = S;
            SVzV[(size_t)jz * 256 + c] = V;
        }
        if (tid < 32) {
            float a = rw[tid][0], g = rw[tid][1];
            float s0 = a, s1 = a * a, s2 = g, s3 = g * g;
#pragma unroll
            for (int m = 1; m < 32; m <<= 1) {
                s0 += __shfl_xor(s0, m, 64); s1 += __shfl_xor(s1, m, 64);
                s2 += __shfl_xor(s2, m, 64); s3 += __shfl_xor(s3, m, 64);
            }
            if (tid == 0) {
                mompart[b * 4 + 0] = s0; mompart[b * 4 + 1] = s1;
                mompart[b * 4 + 2] = s2; mompart[b * 4 + 3] = s3;
            }
        }
    }
}

// ---------------- Gram matrices + SV/mom reduction ----------------
// b<400: Gram jobs. b==400: SV reduce. b==401: moments reduce.
__global__ __launch_bounds__(256)
void gram_kernel(const float* __restrict__ znorm, const float* __restrict__ enorm,
                 float* __restrict__ Gbuf,
                 const float* __restrict__ SVeS, const float* __restrict__ SVeV,
                 const float* __restrict__ SVzS, const float* __restrict__ SVzV,
                 const float* __restrict__ mompart,
                 float* __restrict__ SV, float* __restrict__ mom) {
    int b = blockIdx.x, tid = threadIdx.x;
    __shared__ float xs[16 * 192];           // gram staging (12 KB)
    __shared__ float r1[256], r2[256];

    if (b == 400) {                          // SV reduce (no contention)
        int c = tid;
        float s = 0.f, v = 0.f;
        for (int j = 0; j < NZB; ++j) { s += SVzS[(size_t)j * 256 + c]; v += SVzV[(size_t)j * 256 + c]; }
        SV[c] = s; SV[256 + c] = v;
        s = 0.f; v = 0.f;
        for (int j = 0; j < NCB; ++j) { s += SVeS[(size_t)j * 256 + c]; v += SVeV[(size_t)j * 256 + c]; }
        SV[512 + c] = s; SV[768 + c] = v;
        return;
    }
    if (b == 401) {                          // moments reduce
        int q = tid & 3, grp = tid >> 2;     // 64 groups
        float accE = 0.f, accZ = 0.f;
        for (int j = grp; j < NCB; j += 64) accE += mompart[j * 4 + q];
        for (int j = NCB + grp; j < NCB + NZB; j += 64) accZ += mompart[j * 4 + q];
        r1[tid] = accE; r2[tid] = accZ;
        __syncthreads();
        for (int st = 32; st > 0; st >>= 1) {
            if (grp < st) { r1[tid] += r1[tid + st * 4]; r2[tid] += r2[tid + st * 4]; }
            __syncthreads();
        }
        if (grp == 0) { mom[4 + q] = r1[q]; mom[q] = r2[q]; }
        return;
    }

    const float* X; float* G; int nrows, c0, W, itiles, splitk, local;
    if (b < 32)       { X = enorm; G = Gbuf;         nrows = NE;    c0 = 0;  W = 64;  itiles = 2; splitk = 16; local = b; }
    else if (b < 320) { X = enorm; G = Gbuf + 4096;  nrows = NE;    c0 = 64; W = 192; itiles = 6; splitk = 16; local = b - 32; }
    else if (b < 328) { X = znorm; G = Gbuf + 40960; nrows = T_TOK; c0 = 0;  W = 64;  itiles = 2; splitk = 4;  local = b - 320; }
    else              { X = znorm; G = Gbuf + 45056; nrows = T_TOK; c0 = 64; W = 192; itiles = 6; splitk = 4;  local = b - 328; }
    int ks = local % splitk, rem = local / splitk;
    int i0 = (rem % itiles) * 32, j0 = (rem / itiles) * 64;
    int rows = nrows / splitk, r0 = ks * rows;

    int ti = tid >> 5, tj = tid & 31;
    float acc[4][2] = {};
    for (int rb = 0; rb < rows; rb += 16) {
        __syncthreads();
        int nf4 = 4 * W;
        for (int lin = tid; lin < nf4; lin += 256) {
            int r, f4;
            if (W == 64) { r = lin >> 4; f4 = lin & 15; } else { r = lin / 48; f4 = lin % 48; }
            *(float4*)&xs[r * W + f4 * 4] =
                *(const float4*)&X[(size_t)(r0 + rb + r) * KD + c0 + f4 * 4];
        }
        __syncthreads();
#pragma unroll 4
        for (int r = 0; r < 16; ++r) {
            float4 xi = *(const float4*)&xs[r * W + i0 + ti * 4];
            float xj0 = xs[r * W + j0 + tj * 2];
            float xj1 = xs[r * W + j0 + tj * 2 + 1];
#pragma unroll
            for (int a = 0; a < 4; ++a) {
                acc[a][0] = fmaf(xi[a], xj0, acc[a][0]);
                acc[a][1] = fmaf(xi[a], xj1, acc[a][1]);
            }
        }
    }
#pragma unroll
    for (int a = 0; a < 4; ++a) {
        int i = i0 + ti * 4 + a;
        atomicAdd(&G[i * W + j0 + tj * 2],     acc[a][0]);
        atomicAdd(&G[i * W + j0 + tj * 2 + 1], acc[a][1]);
    }
}

// ---------------- fused MFMA GEMM ----------------
// grid: x = token-block (32), y = code-block (128).
__global__ __launch_bounds__(256, 4)
void gemm_fused_kernel(const short* __restrict__ Zs, const short* __restrict__ Es,
                       const float* __restrict__ z2s, const float* __restrict__ e2s,
                       u64* __restrict__ packed, float* __restrict__ scal,
                       float* __restrict__ part_m, float* __restrict__ part_z,
                       float* __restrict__ part_w,
                       float* __restrict__ candD, int* __restrict__ candN,
                       int* __restrict__ ncand) {
    __shared__ __align__(16) short As[128 * 64];   // [token_row][k] 64 bf16/row
    __shared__ __align__(16) short Bs[128 * 64];   // [code_row][k]
    const int tid = threadIdx.x;
    const int lane = tid & 63, wid = tid >> 6;
    const int wm = wid >> 1, wn = wid & 1;         // wave tile: 64(tok) x 64(code)
    const int t0 = blockIdx.x * 128, n0 = blockIdx.y * 128;

    f32x4 acc[4][4];
#pragma unroll
    for (int bi = 0; bi < 4; ++bi)
#pragma unroll
        for (int bj = 0; bj < 4; ++bj) {
            f32x4 zz = {0.f, 0.f, 0.f, 0.f};
            acc[bi][bj] = zz;
        }

    auto stage = [&](int k0) {
        const int rb0 = wid * 32;
#pragma unroll
        for (int c2 = 0; c2 < 4; ++c2) {
            int rb = rb0 + c2 * 8;
            int row = rb + (lane >> 3);
            int q = (lane & 7) ^ (lane >> 3);   // XOR-quad swizzle (rb%8==0)
            async_load16(Zs + (size_t)(t0 + row) * K3 + k0 + q * 8, &As[rb * 64]);
            async_load16(Es + (size_t)(n0 + row) * K3 + k0 + q * 8, &Bs[rb * 64]);
        }
    };
    auto compute_half = [&](int s) {
        bf16x8 bfv[4];
#pragma unroll
        for (int bj = 0; bj < 4; ++bj) {
            int brow = wn * 64 + bj * 16 + (lane & 15);
            int q = ((s << 2) | (lane >> 4)) ^ (brow & 7);
            bfv[bj] = *reinterpret_cast<const bf16x8*>(&Bs[brow * 64 + q * 8]);
        }
#pragma unroll
        for (int bi = 0; bi < 4; ++bi) {
            int arow = wm * 64 + bi * 16 + (lane & 15);
            int q = ((s << 2) | (lane >> 4)) ^ (arow & 7);
            bf16x8 af = *reinterpret_cast<const bf16x8*>(&As[arow * 64 + q * 8]);
#pragma unroll
            for (int bj = 0; bj < 4; ++bj)
                acc[bi][bj] = __builtin_amdgcn_mfma_f32_16x16x32_bf16(
                    af, bfv[bj], acc[bi][bj], 0, 0, 0);
        }
    };

    int k0 = 0;
    for (int r = 0; r < 12; ++r) {             // acc = -2*(dot_k + dot_g)
        stage(k0); __syncthreads();
        compute_half(0); compute_half(1);
        __syncthreads(); k0 += 64;
    }

    // ---- epilogue ----
    char* lds = (char*)As;
    u64*   tokmin = (u64*)lds;                 // [128][2]   2048 B
    float* bmf    = (float*)(lds + 2048);      // [128]       512 B
    float* bthr   = (float*)(lds + 2560);      // [128]       512 B
    float* pzw    = (float*)(lds + 3072);      // [128][2][2] 2048 B

    float e2sv[4];
#pragma unroll
    for (int bj = 0; bj < 4; ++bj)
        e2sv[bj] = e2s[n0 + wn * 64 + bj * 16 + (lane & 15)];

    // pass 1: per-token wave-local packed min (d,n)
#pragma unroll
    for (int bi = 0; bi < 4; ++bi) {
        u64 pmin[4] = {~0ull, ~0ull, ~0ull, ~0ull};
        f32x4 z4 = *reinterpret_cast<const f32x4*>(
            &z2s[t0 + wm * 64 + bi * 16 + (lane >> 4) * 4]);
#pragma unroll
        for (int reg = 0; reg < 4; ++reg) {
#pragma unroll
            for (int bj = 0; bj < 4; ++bj) {
                float d = z4[reg] + e2sv[bj] + acc[bi][bj][reg];
                int n = n0 + wn * 64 + bj * 16 + (lane & 15);
                u64 pv = (((u64)__float_as_uint(d)) << 32) | (unsigned)n;
                if (pv < pmin[reg]) pmin[reg] = pv;
            }
        }
#pragma unroll
        for (int m = 1; m < 16; m <<= 1)
#pragma unroll
            for (int reg = 0; reg < 4; ++reg) {
                u64 o = __shfl_xor(pmin[reg], m, 64);
                if (o < pmin[reg]) pmin[reg] = o;
            }
        if ((lane & 15) == 0) {
#pragma unroll
            for (int reg = 0; reg < 4; ++reg) {
                int tl = wm * 64 + bi * 16 + (lane >> 4) * 4 + reg;
                tokmin[tl * 2 + wn] = pmin[reg];
            }
        }
    }
    __syncthreads();

    // owner step: block min -> global atomicMin (returns old => best-so-far)
    if (tid < 128) {
        int tl = tid;
        u64 bm = tokmin[tl * 2], b1 = tokmin[tl * 2 + 1];
        if (b1 < bm) bm = b1;
        u64 old = atomicMin(&packed[t0 + tl], bm);
        u64 gb = (old < bm) ? old : bm;
        float d_bmin = __uint_as_float((unsigned)(bm >> 32));
        bmf[tl] = -100.f * d_bmin;
        bthr[tl] = __uint_as_float((unsigned)(gb >> 32)) + DCUT;
    }
    __syncthreads();

    // pass 2: block-level softmax partials + candidate capture
#pragma unroll
    for (int bi = 0; bi < 4; ++bi) {
        float ez[4] = {0.f, 0.f, 0.f, 0.f}, ew[4] = {0.f, 0.f, 0.f, 0.f};
        f32x4 z4 = *reinterpret_cast<const f32x4*>(
            &z2s[t0 + wm * 64 + bi * 16 + (lane >> 4) * 4]);
#pragma unroll
        for (int reg = 0; reg < 4; ++reg) {
            int tl = wm * 64 + bi * 16 + (lane >> 4) * 4 + reg;
            int t = t0 + tl;
            float m_b = bmf[tl], thr = bthr[tl];
#pragma unroll
            for (int bj = 0; bj < 4; ++bj) {
                float d = z4[reg] + e2sv[bj] + acc[bi][bj][reg];
                float a = -100.f * d;
                float e = __expf(a - m_b);
                ez[reg] += e;
                ew[reg] = fmaf(a, e, ew[reg]);
                if (d <= thr) {
                    int pos = atomicAdd(&ncand[t], 1);
                    if (pos < CAP) {
                        candD[(size_t)t * CAP + pos] = d;
                        candN[(size_t)t * CAP + pos] = n0 + wn * 64 + bj * 16 + (lane & 15);
                    }
                }
            }
        }
#pragma unroll
        for (int m = 1; m < 16; m <<= 1)
#pragma unroll
            for (int reg = 0; reg < 4; ++reg) {
                ez[reg] += __shfl_xor(ez[reg], m, 64);
                ew[reg] += __shfl_xor(ew[reg], m, 64);
            }
        if ((lane & 15) == 0) {
#pragma unroll
            for (int reg = 0; reg < 4; ++reg) {
                int tl = wm * 64 + bi * 16 + (lane >> 4) * 4 + reg;
                pzw[(tl * 2 + wn) * 2 + 0] = ez[reg];
                pzw[(tl * 2 + wn) * 2 + 1] = ew[reg];
            }
        }
    }
    __syncthreads();

    // owner step 2: write per-block partials (coalesced)
    if (tid < 128) {
        int tl = tid;
        size_t o = (size_t)blockIdx.y * T_TOK + t0 + tl;
        part_m[o] = bmf[tl];
        part_z[o] = pzw[tl * 4 + 0] + pzw[tl * 4 + 2];
        part_w[o] = pzw[tl * 4 + 1] + pzw[tl * 4 + 3];
    }
}

// ---------------- combine + zq fused: 64 blocks x 64 tokens ----------------
__global__ __launch_bounds__(256)
void combine_zq_kernel(const float* __restrict__ part_m, const float* __restrict__ part_z,
                       const float* __restrict__ part_w, const u64* __restrict__ packed,
                       float* __restrict__ m_arr, float* __restrict__ Z_arr,
                       const float* __restrict__ enorm, const float* __restrict__ znorm,
                       float* __restrict__ out, float* __restrict__ scal) {
    __shared__ float sm[64][4], sz[64][4], sw[64][4];
    __shared__ int idxs[64];
    __shared__ float q_lds[256][33];
    __shared__ float red[256];
    int tid = threadIdx.x, tl = tid & 63, q = tid >> 6;
    int tbase = blockIdx.x * 64;
    int t = tbase + tl;
    // phase 1: online-softmax combine (4-way split over 128 n-blocks)
    float m = -3.0e38f, Z = 0.f, W = 0.f;
    for (int nb = q * 32; nb < q * 32 + 32; ++nb) {
        size_t o = (size_t)nb * T_TOK + t;
        float mb = part_m[o], zb = part_z[o], wb = part_w[o];
        if (mb > m) { float s = __expf(m - mb); Z *= s; W *= s; m = mb; }
        float s2 = __expf(mb - m);
        Z = fmaf(zb, s2, Z); W = fmaf(wb, s2, W);
    }
    sm[tl][q] = m; sz[tl][q] = Z; sw[tl][q] = W;
    __syncthreads();
    if (tid < 64) {
        float M = sm[tid][0], Zt = sz[tid][0], Wt = sw[tid][0];
#pragma unroll
        for (int qq = 1; qq < 4; ++qq) {
            float mb = sm[tid][qq], Zb = sz[tid][qq], Wb = sw[tid][qq];
            if (mb > M) { float s = __expf(M - mb); Zt *= s; Wt *= s; M = mb; }
            float s2 = __expf(mb - M);
            Zt = fmaf(Zb, s2, Zt); Wt = fmaf(Wb, s2, Wt);
        }
        int tt = tbase + tid;
        m_arr[tt] = M; Z_arr[tt] = Zt;
        u64 pv = packed[tt];
        int idx = (int)(pv & 0xFFFFFFFFull);
        idxs[tid] = idx;
        out[1048581 + tt] = (float)idx;
        float ent = M + logf(Zt) - Wt / Zt;
#pragma unroll
        for (int mm = 1; mm < 64; mm <<= 1) ent += __shfl_xor(ent, mm, 64);
        if (tid == 0) atomicAdd(&scal[3], ent);
    }
    __syncthreads();
    // phase 2: z_q gather + transpose + vq loss, two 32-token passes
    float sdq = 0.f;
    for (int pass = 0; pass < 2; ++pass) {
        int t0 = tbase + pass * 32;
        for (int tl2 = 0; tl2 < 32; ++tl2) {
            int tt = t0 + tl2;
            float qv = enorm[(size_t)idxs[pass * 32 + tl2] * KD + tid];
            q_lds[tid][tl2] = qv;
            float zc = znorm[(size_t)tt * KD + tid];
            float df = qv - zc;
            sdq = fmaf(df, df, sdq);
        }
        __syncthreads();
        int bb = t0 >> 10, hw0 = t0 & 1023;
        int cg = tid >> 5, hwl = tid & 31;
        for (int c0 = 0; c0 < 256; c0 += 8) {
            int c = c0 + cg;
            out[(((size_t)(bb * 256 + c)) << 10) + hw0 + hwl] = q_lds[c][hwl];
        }
        __syncthreads();
    }
    red[tid] = sdq;
    __syncthreads();
    for (int s = 128; s > 0; s >>= 1) { if (tid < s) red[tid] += red[tid + s]; __syncthreads(); }
    if (tid == 0) atomicAdd(&scal[2], red[0]);
}

// ---------------- avg_probs scatter from candidates ----------------
__global__ void avg_scatter_kernel(const float* __restrict__ candD, const int* __restrict__ candN,
                                   const int* __restrict__ ncand, const float* __restrict__ m_arr,
                                   const float* __restrict__ Z_arr, float* __restrict__ avg_num) {
    int t = blockIdx.x, lane = threadIdx.x;  // 64
    int nc = min(ncand[t], CAP);
    float m = m_arr[t], Z = Z_arr[t];
    for (int i = lane; i < nc; i += 64) {
        float a = -100.f * candD[(size_t)t * CAP + i];
        atomicAdd(&avg_num[candN[(size_t)t * CAP + i]], __expf(a - m) / Z);
    }
}

// ---------------- final scalars (incl. closed-form d-norms) ----------------
__global__ void finalize_kernel(const float* __restrict__ avg_num, const float* __restrict__ scal,
                                const float* __restrict__ G, const float* __restrict__ SV,
                                const float* __restrict__ mom, float* __restrict__ out) {
    __shared__ float red[256];
    int tid = threadIdx.x;
    float s = 0.f;
    for (int n = tid; n < NE; n += 256) {
        float avg = avg_num[n] * (1.f / 4096.f);
        s += avg * logf(avg + 1e-5f);
    }
    red[tid] = s; __syncthreads();
    for (int st = 128; st > 0; st >>= 1) { if (tid < st) red[tid] += red[tid + st]; __syncthreads(); }
    float avg_ent_neg = (tid == 0) ? red[0] : 0.f;
    __syncthreads();

    const float* G_ek = G;
    const float* G_eg = G + 4096;
    const float* G_zk = G + 40960;
    const float* G_zg = G + 45056;
    float rk = 0.f, rg = 0.f;
    for (int i = tid; i < 4096; i += 256)  rk = fmaf(G_zk[i], G_ek[i], rk);
    for (int i = tid; i < 36864; i += 256) rg = fmaf(G_zg[i], G_eg[i], rg);
    {
        int c = tid;
        float v = SV[256 + c] * SV[512 + c] + SV[c] * SV[768 + c];
        if (c < 64) rk -= v; else rg -= v;
    }
    red[tid] = 4.f * rk; __syncthreads();
    for (int st = 128; st > 0; st >>= 1) { if (tid < st) red[tid] += red[tid + st]; __syncthreads(); }
    float red_k = red[0];
    __syncthreads();
    red[tid] = 4.f * rg; __syncthreads();
    for (int st = 128; st > 0; st >>= 1) { if (tid < st) red[tid] += red[tid + st]; __syncthreads(); }
    float red_g = red[0];

    if (tid == 0) {
        float term1k = NE * mom[1] + 2.f * mom[0] * mom[4] + T_TOK * mom[5];
        float term1g = NE * mom[3] + 2.f * mom[2] * mom[6] + T_TOK * mom[7];
        float sdk2 = term1k + red_k;
        float sdg2 = term1g + red_g;
        float avg_ent = -avg_ent_neg;
        float se = scal[3] * (1.f / 4096.f);
        float vq = scal[2] * (1.f / 1048576.f);
        out[1048576] = vq;
        out[1048577] = 0.25f * vq;
        out[1048578] = 0.1f * (se - avg_ent);
        out[1048579] = sdk2 * (1.f / 4096.f);
        out[1048580] = sdg2 * (1.f / 4096.f);
    }
}

// ---------------- host ----------------
extern "C" void kernel_launch(void* const* d_in, const int* in_sizes, int n_in,
                              void* d_out, int out_size, void* d_ws, size_t ws_size,
                              hipStream_t stream) {
    const float* z  = (const float*)d_in[0];
    const float* wk = (const float*)d_in[1];
    const float* wg = (const float*)d_in[2];
    float* out = (float*)d_out;

    char* ws = (char*)d_ws;
    size_t off = 0;
    auto alloc = [&](size_t bytes) {
        void* p = ws + off;
        off += (bytes + 255) & ~(size_t)255;
        return p;
    };
    float* enorm  = (float*)alloc((size_t)NE * KD * 4);        // 16.78 MB
    float* znorm  = (float*)alloc((size_t)T_TOK * KD * 4);     //  4.19 MB
    short* Es     = (short*)alloc((size_t)NE * K3 * 2);        // 25.17 MB
    short* Zs     = (short*)alloc((size_t)T_TOK * K3 * 2);     //  6.29 MB
    float* e2k    = (float*)alloc(NE * 4);
    float* e2s    = (float*)alloc(NE * 4);
    float* z2k    = (float*)alloc(T_TOK * 4);
    float* z2s    = (float*)alloc(T_TOK * 4);
    u64*   packed = (u64*)alloc(T_TOK * 8);
    float* m_arr  = (float*)alloc(T_TOK * 4);
    float* Z_arr  = (float*)alloc(T_TOK * 4);
    int*   ncand  = (int*)alloc(T_TOK * 4);
    float* part_m = (float*)alloc((size_t)(NE / 128) * T_TOK * 4);  // 2.10 MB
    float* part_z = (float*)alloc((size_t)(NE / 128) * T_TOK * 4);  // 2.10 MB
    float* part_w = (float*)alloc((size_t)(NE / 128) * T_TOK * 4);  // 2.10 MB
    float* candD  = (float*)alloc((size_t)T_TOK * CAP * 4);    // 12.58 MB
    int*   candN  = (int*)alloc((size_t)T_TOK * CAP * 4);      // 12.58 MB
    float* avg_num= (float*)alloc(NE * 4);
    float* scal   = (float*)alloc(8 * 4);
    float* Gbuf   = (float*)alloc(81920 * 4);                  // Gram blocks
    float* SV     = (float*)alloc(1024 * 4);
    float* momv   = (float*)alloc(8 * 4);
    float* SVeS   = (float*)alloc((size_t)NCB * 256 * 4);      // 0.52 MB
    float* SVeV   = (float*)alloc((size_t)NCB * 256 * 4);
    float* SVzS   = (float*)alloc((size_t)NZB * 256 * 4);      // 0.13 MB
    float* SVzV   = (float*)alloc((size_t)NZB * 256 * 4);
    float* mompart= (float*)alloc((size_t)(NCB + NZB) * 4 * 4);

    megaprep_kernel<<<NCB + NZB + 8, 256, 0, stream>>>(
        wk, wg, z, enorm, e2k, e2s, Es, znorm, z2k, z2s, Zs,
        SVeS, SVeV, SVzS, SVzV, mompart, packed, avg_num, ncand, scal, Gbuf);
    gram_kernel<<<402, 256, 0, stream>>>(znorm, enorm, Gbuf,
                                         SVeS, SVeV, SVzS, SVzV, mompart, SV, momv);

    dim3 gg(T_TOK / 128, NE / 128);   // x = token-block, y = code-block
    gemm_fused_kernel<<<gg, 256, 0, stream>>>(Zs, Es, z2s, e2s,
                                              packed, scal, part_m, part_z, part_w,
                                              candD, candN, ncand);
    combine_zq_kernel<<<T_TOK / 64, 256, 0, stream>>>(part_m, part_z, part_w, packed,
                                                      m_arr, Z_arr, enorm, znorm, out, scal);
    avg_scatter_kernel<<<T_TOK, 64, 0, stream>>>(candD, candN, ncand, m_arr, Z_arr, avg_num);
    finalize_kernel<<<1, 256, 0, stream>>>(avg_num, scal, Gbuf, SV, momv, out);
}

// Round 9
// 412.244 us; speedup vs baseline: 1.1484x; 1.0642x over previous
//
#include <hip/hip_runtime.h>

// VectorQuantizer forward, MI355X. Split-bf16 MFMA GEMM (hi/lo, 3 products,
// K extended 256->768). Epilogue: argmin + per-block online-softmax partials
// (exact entropy) + racy-shrinking-threshold candidate capture. d^2-norm split
// in closed form (Gram + colsums + moments). R9: 3 kernels total —
// megaprep | gemm+gram (gram overlapped as tail blocks) |
// combine+zq+scatter with last-block finalize (threadfence + counter).
// T=4096 tokens, NE=16384 codes.

#define T_TOK 4096
#define NE    16384
#define KD    256
#define K3    768          // 3x split-extended K
#define CAP   768          // candidate slots per token (avg_probs only)
#define DCUT  0.15f        // capture window above best-so-far global min

#define NCB   512          // code prep blocks (32 rows each)
#define NZB   128          // z prep blocks (32 tokens each)
#define NGEMM 4096         // gemm blocks (32 x 128)

typedef __attribute__((ext_vector_type(8))) short bf16x8;
typedef __attribute__((ext_vector_type(4))) float f32x4;
typedef unsigned long long u64;

__device__ __forceinline__ short f2bf(float f) {
    unsigned u = __float_as_uint(f);
    u = (u + 0x7FFFu + ((u >> 16) & 1u)) >> 16;   // round-to-nearest-even
    return (short)u;
}
__device__ __forceinline__ float bf2f(short s) {
    return __uint_as_float(((unsigned)(unsigned short)s) << 16);
}

__device__ __forceinline__ void async_load16(const void* g, void* l) {
    __builtin_amdgcn_global_load_lds(
        (const __attribute__((address_space(1))) void*)g,
        (__attribute__((address_space(3))) void*)l, 16, 0, 0);
}

// ---------------- megaprep: codes | z | init, branch on blockIdx ----------------
__global__ __launch_bounds__(256)
void megaprep_kernel(const float* __restrict__ wk, const float* __restrict__ wg,
                     const float* __restrict__ z,
                     float* __restrict__ enorm, float* __restrict__ e2k,
                     float* __restrict__ e2s, short* __restrict__ Es,
                     float* __restrict__ znorm, float* __restrict__ z2k,
                     float* __restrict__ z2s, short* __restrict__ Zs,
                     float* __restrict__ SVeS, float* __restrict__ SVeV,
                     float* __restrict__ SVzS, float* __restrict__ SVzV,
                     float* __restrict__ mompart,
                     u64* __restrict__ packed, float* __restrict__ avg_num,
                     int* __restrict__ ncand, float* __restrict__ scal,
                     float* __restrict__ G, int* __restrict__ done_ctr) {
    int b = blockIdx.x, tid = threadIdx.x;
    if (b >= NCB + NZB) {                    // ---- init branch ----
        int gid = (b - NCB - NZB) * 256 + tid;
        for (int i = gid; i < 81920; i += 2048) G[i] = 0.f;
        for (int i = gid; i < NE; i += 2048) avg_num[i] = 0.f;
        for (int i = gid; i < T_TOK; i += 2048) { packed[i] = ~0ull; ncand[i] = 0; }
        if (gid < 8) scal[gid] = 0.f;
        if (gid == 8) *done_ctr = 0;
        return;
    }

    __shared__ float xs[32][257];            // 32.9 KB
    __shared__ float ps[32][8];
    __shared__ float rnorm[32][2];
    __shared__ float rw[32][2];

    if (b < NCB) {                           // ---- codes branch ----
        int n0 = b * 32;
#pragma unroll
        for (int i = 0; i < 8; ++i) {
            int idx = tid + i * 256;
            xs[idx >> 6][idx & 63] = wk[(size_t)n0 * 64 + idx];
        }
#pragma unroll
        for (int i = 0; i < 24; ++i) {
            int idx = tid + i * 256;
            xs[idx / 192][64 + idx % 192] = wg[(size_t)n0 * 192 + idx];
        }
        __syncthreads();
        {
            int r = tid & 31, part = tid >> 5;
            float s = 0.f;
            for (int j = 0; j < 32; ++j) { float v = xs[r][part * 32 + j]; s = fmaf(v, v, s); }
            ps[r][part] = s;
        }
        __syncthreads();
        if (tid < 32) {
            float sk = ps[tid][0] + ps[tid][1];
            float sg = ps[tid][2] + ps[tid][3] + ps[tid][4] + ps[tid][5] + ps[tid][6] + ps[tid][7];
            float nk = fmaxf(sqrtf(sk), 1e-12f), ng = fmaxf(sqrtf(sg), 1e-12f);
            float ek2 = sk / (nk * nk), eg2 = sg / (ng * ng);
            rnorm[tid][0] = 1.f / nk; rnorm[tid][1] = 1.f / ng;
            rw[tid][0] = ek2; rw[tid][1] = eg2;
            e2k[n0 + tid] = ek2; e2s[n0 + tid] = ek2 + eg2;
        }
        __syncthreads();
        int c = tid;
        for (int i = 0; i < 32; ++i) {
            float y = xs[i][c] * rnorm[i][(c < 64) ? 0 : 1];
            enorm[(size_t)(n0 + i) * KD + c] = y;
            short h = f2bf(y);          float hf = bf2f(h);
            short l = f2bf(y - hf);
            short sh = f2bf(-2.f * hf), sl = f2bf(-2.f * bf2f(l));
            short* Er = Es + (size_t)(n0 + i) * K3;
            if (c < 64) { Er[c] = sh; Er[64 + c] = sl; Er[128 + c] = sh; }
            else { int cc = c - 64; Er[192 + cc] = sh; Er[384 + cc] = sl; Er[576 + cc] = sh; }
        }
        {
            int sel = (c < 64) ? 0 : 1;
            float S = 0.f, V = 0.f;
            for (int r = 0; r < 32; ++r) {
                float y = xs[r][c] * rnorm[r][sel];
                S += y; V = fmaf(rw[r][sel], y, V);
            }
            SVeS[(size_t)b * 256 + c] = S;
            SVeV[(size_t)b * 256 + c] = V;
        }
        if (tid < 32) {
            float a = rw[tid][0], g = rw[tid][1];
            float s0 = a, s1 = a * a, s2 = g, s3 = g * g;
#pragma unroll
            for (int m = 1; m < 32; m <<= 1) {
                s0 += __shfl_xor(s0, m, 64); s1 += __shfl_xor(s1, m, 64);
                s2 += __shfl_xor(s2, m, 64); s3 += __shfl_xor(s3, m, 64);
            }
            if (tid == 0) {
                mompart[b * 4 + 0] = s0; mompart[b * 4 + 1] = s1;
                mompart[b * 4 + 2] = s2; mompart[b * 4 + 3] = s3;
            }
        }
    } else {                                 // ---- z branch ----
        int jz = b - NCB;
        int t0 = jz * 32;
        int bb = t0 >> 10, hw0 = t0 & 1023;
#pragma unroll
        for (int i = 0; i < 32; ++i) {
            int idx = tid + i * 256;
            int cc = idx >> 5, hwl = idx & 31;
            xs[hwl][cc] = z[(((size_t)bb * 256 + cc) << 10) + hw0 + hwl];
        }
        __syncthreads();
        {
            int r = tid & 31, part = tid >> 5;
            float s = 0.f;
            for (int j = 0; j < 32; ++j) { float v = xs[r][part * 32 + j]; s = fmaf(v, v, s); }
            ps[r][part] = s;
        }
        __syncthreads();
        if (tid < 32) {
            float sk = ps[tid][0] + ps[tid][1];
            float sg = ps[tid][2] + ps[tid][3] + ps[tid][4] + ps[tid][5] + ps[tid][6] + ps[tid][7];
            float nk = fmaxf(sqrtf(sk), 1e-12f), ng = fmaxf(sqrtf(sg), 1e-12f);
            float zk2 = sk / (nk * nk), zg2 = sg / (ng * ng);
            rnorm[tid][0] = 1.f / nk; rnorm[tid][1] = 1.f / ng;
            rw[tid][0] = zk2; rw[tid][1] = zg2;
            z2k[t0 + tid] = zk2; z2s[t0 + tid] = zk2 + zg2;
        }
        __syncthreads();
        int c = tid;
        for (int i = 0; i < 32; ++i) {
            float y = xs[i][c] * rnorm[i][(c < 64) ? 0 : 1];
            znorm[(size_t)(t0 + i) * KD + c] = y;
            short h = f2bf(y);      float hf = bf2f(h);
            short l = f2bf(y - hf);
            short* Zr = Zs + (size_t)(t0 + i) * K3;
            if (c < 64) { Zr[c] = h; Zr[64 + c] = h; Zr[128 + c] = l; }
            else { int cc = c - 64; Zr[192 + cc] = h; Zr[384 + cc] = h; Zr[576 + cc] = l; }
        }
        {
            int sel = (c < 64) ? 0 : 1;
            float S = 0.f, V = 0.f;
            for (int r = 0; r < 32; ++r) {
                float y = xs[r][c] * rnorm[r][sel];
                S += y; V = fmaf(rw[r][sel], y, V);
            }
            SVzS[(size_t)jz * 256 + c] = S;
            SVzV[(size_t)jz * 256 + c] = V;
        }
        if (tid < 32) {
            float a = rw[tid][0], g = rw[tid][1];
            float s0 = a, s1 = a * a, s2 = g, s3 = g * g;
#pragma unroll
            for (int m = 1; m < 32; m <<= 1) {
                s0 += __shfl_xor(s0, m, 64); s1 += __shfl_xor(s1, m, 64);
                s2 += __shfl_xor(s2, m, 64); s3 += __shfl_xor(s3, m, 64);
            }
            if (tid == 0) {
                mompart[b * 4 + 0] = s0; mompart[b * 4 + 1] = s1;
                mompart[b * 4 + 2] = s2; mompart[b * 4 + 3] = s3;
            }
        }
    }
}

// ---------------- fused GEMM + Gram (gram as tail blocks, overlapped) ----------------
// gid < NGEMM: gemm, t0=(gid%32)*128, n0=(gid/32)*128.
// gid-NGEMM in [0,400): Gram jobs; ==400: SV reduce; ==401: moments reduce.
__global__ __launch_bounds__(256, 4)
void gemm_gram_kernel(const short* __restrict__ Zs, const short* __restrict__ Es,
                      const float* __restrict__ z2s, const float* __restrict__ e2s,
                      u64* __restrict__ packed, float* __restrict__ scal,
                      float* __restrict__ part_m, float* __restrict__ part_z,
                      float* __restrict__ part_w,
                      float* __restrict__ candD, int* __restrict__ candN,
                      int* __restrict__ ncand,
                      const float* __restrict__ znorm, const float* __restrict__ enorm,
                      float* __restrict__ Gbuf,
                      const float* __restrict__ SVeS, const float* __restrict__ SVeV,
                      const float* __restrict__ SVzS, const float* __restrict__ SVzV,
                      const float* __restrict__ mompart,
                      float* __restrict__ SV, float* __restrict__ mom) {
    __shared__ __align__(16) char smem[32768];
    const int gid = blockIdx.x, tid = threadIdx.x;

    if (gid >= NGEMM) {                       // =============== GRAM path ===============
        int b = gid - NGEMM;
        float* xs = (float*)smem;             // 16*192 floats = 12.3 KB
        float* r1 = (float*)(smem + 12288);
        float* r2 = (float*)(smem + 13312);

        if (b == 400) {                       // SV reduce
            int c = tid;
            float s = 0.f, v = 0.f;
            for (int j = 0; j < NZB; ++j) { s += SVzS[(size_t)j * 256 + c]; v += SVzV[(size_t)j * 256 + c]; }
            SV[c] = s; SV[256 + c] = v;
            s = 0.f; v = 0.f;
            for (int j = 0; j < NCB; ++j) { s += SVeS[(size_t)j * 256 + c]; v += SVeV[(size_t)j * 256 + c]; }
            SV[512 + c] = s; SV[768 + c] = v;
            return;
        }
        if (b == 401) {                       // moments reduce
            int q = tid & 3, grp = tid >> 2;
            float accE = 0.f, accZ = 0.f;
            for (int j = grp; j < NCB; j += 64) accE += mompart[j * 4 + q];
            for (int j = NCB + grp; j < NCB + NZB; j += 64) accZ += mompart[j * 4 + q];
            r1[tid] = accE; r2[tid] = accZ;
            __syncthreads();
            for (int st = 32; st > 0; st >>= 1) {
                if (grp < st) { r1[tid] += r1[tid + st * 4]; r2[tid] += r2[tid + st * 4]; }
                __syncthreads();
            }
            if (grp == 0) { mom[4 + q] = r1[q]; mom[q] = r2[q]; }
            return;
        }

        const float* X; float* G; int nrows, c0, W, itiles, splitk, local;
        if (b < 32)       { X = enorm; G = Gbuf;         nrows = NE;    c0 = 0;  W = 64;  itiles = 2; splitk = 16; local = b; }
        else if (b < 320) { X = enorm; G = Gbuf + 4096;  nrows = NE;    c0 = 64; W = 192; itiles = 6; splitk = 16; local = b - 32; }
        else if (b < 328) { X = znorm; G = Gbuf + 40960; nrows = T_TOK; c0 = 0;  W = 64;  itiles = 2; splitk = 4;  local = b - 320; }
        else              { X = znorm; G = Gbuf + 45056; nrows = T_TOK; c0 = 64; W = 192; itiles = 6; splitk = 4;  local = b - 328; }
        int ks = local % splitk, rem = local / splitk;
        int i0 = (rem % itiles) * 32, j0 = (rem / itiles) * 64;
        int rows = nrows / splitk, r0 = ks * rows;

        int ti = tid >> 5, tj = tid & 31;
        float acc[4][2] = {};
        for (int rb = 0; rb < rows; rb += 16) {
            __syncthreads();
            int nf4 = 4 * W;
            for (int lin = tid; lin < nf4; lin += 256) {
                int r, f4;
                if (W == 64) { r = lin >> 4; f4 = lin & 15; } else { r = lin / 48; f4 = lin % 48; }
                *(float4*)&xs[r * W + f4 * 4] =
                    *(const float4*)&X[(size_t)(r0 + rb + r) * KD + c0 + f4 * 4];
            }
            __syncthreads();
#pragma unroll 4
            for (int r = 0; r < 16; ++r) {
                float4 xi = *(const float4*)&xs[r * W + i0 + ti * 4];
                float xj0 = xs[r * W + j0 + tj * 2];
                float xj1 = xs[r * W + j0 + tj * 2 + 1];
#pragma unroll
                for (int a = 0; a < 4; ++a) {
                    acc[a][0] = fmaf(xi[a], xj0, acc[a][0]);
                    acc[a][1] = fmaf(xi[a], xj1, acc[a][1]);
                }
            }
        }
#pragma unroll
        for (int a = 0; a < 4; ++a) {
            int i = i0 + ti * 4 + a;
            atomicAdd(&G[i * W + j0 + tj * 2],     acc[a][0]);
            atomicAdd(&G[i * W + j0 + tj * 2 + 1], acc[a][1]);
        }
        return;
    }

    // =============== GEMM path ===============
    short* As = (short*)smem;                 // [128][64]
    short* Bs = As + 128 * 64;
    const int lane = tid & 63, wid = tid >> 6;
    const int wm = wid >> 1, wn = wid & 1;
    const int t0 = (gid & 31) * 128, n0 = (gid >> 5) * 128;

    f32x4 acc[4][4];
#pragma unroll
    for (int bi = 0; bi < 4; ++bi)
#pragma unroll
        for (int bj = 0; bj < 4; ++bj) {
            f32x4 zz = {0.f, 0.f, 0.f, 0.f};
            acc[bi][bj] = zz;
        }

    auto stage = [&](int k0) {
        const int rb0 = wid * 32;
#pragma unroll
        for (int c2 = 0; c2 < 4; ++c2) {
            int rb = rb0 + c2 * 8;
            int row = rb + (lane >> 3);
            int q = (lane & 7) ^ (lane >> 3);   // XOR-quad swizzle (rb%8==0)
            async_load16(Zs + (size_t)(t0 + row) * K3 + k0 + q * 8, &As[rb * 64]);
            async_load16(Es + (size_t)(n0 + row) * K3 + k0 + q * 8, &Bs[rb * 64]);
        }
    };
    auto compute_half = [&](int s) {
        bf16x8 bfv[4];
#pragma unroll
        for (int bj = 0; bj < 4; ++bj) {
            int brow = wn * 64 + bj * 16 + (lane & 15);
            int q = ((s << 2) | (lane >> 4)) ^ (brow & 7);
            bfv[bj] = *reinterpret_cast<const bf16x8*>(&Bs[brow * 64 + q * 8]);
        }
#pragma unroll
        for (int bi = 0; bi < 4; ++bi) {
            int arow = wm * 64 + bi * 16 + (lane & 15);
            int q = ((s << 2) | (lane >> 4)) ^ (arow & 7);
            bf16x8 af = *reinterpret_cast<const bf16x8*>(&As[arow * 64 + q * 8]);
#pragma unroll
            for (int bj = 0; bj < 4; ++bj)
                acc[bi][bj] = __builtin_amdgcn_mfma_f32_16x16x32_bf16(
                    af, bfv[bj], acc[bi][bj], 0, 0, 0);
        }
    };

    int k0 = 0;
    for (int r = 0; r < 12; ++r) {
        stage(k0); __syncthreads();
        compute_half(0); compute_half(1);
        __syncthreads(); k0 += 64;
    }

    // ---- epilogue ----
    u64*   tokmin = (u64*)smem;               // [128][2]   2048 B
    float* bmf    = (float*)(smem + 2048);    // [128]
    float* bthr   = (float*)(smem + 2560);    // [128]
    float* pzw    = (float*)(smem + 3072);    // [128][2][2]

    float e2sv[4];
#pragma unroll
    for (int bj = 0; bj < 4; ++bj)
        e2sv[bj] = e2s[n0 + wn * 64 + bj * 16 + (lane & 15)];

#pragma unroll
    for (int bi = 0; bi < 4; ++bi) {
        u64 pmin[4] = {~0ull, ~0ull, ~0ull, ~0ull};
        f32x4 z4 = *reinterpret_cast<const f32x4*>(
            &z2s[t0 + wm * 64 + bi * 16 + (lane >> 4) * 4]);
#pragma unroll
        for (int reg = 0; reg < 4; ++reg) {
#pragma unroll
            for (int bj = 0; bj < 4; ++bj) {
                float d = z4[reg] + e2sv[bj] + acc[bi][bj][reg];
                int n = n0 + wn * 64 + bj * 16 + (lane & 15);
                u64 pv = (((u64)__float_as_uint(d)) << 32) | (unsigned)n;
                if (pv < pmin[reg]) pmin[reg] = pv;
            }
        }
#pragma unroll
        for (int m = 1; m < 16; m <<= 1)
#pragma unroll
            for (int reg = 0; reg < 4; ++reg) {
                u64 o = __shfl_xor(pmin[reg], m, 64);
                if (o < pmin[reg]) pmin[reg] = o;
            }
        if ((lane & 15) == 0) {
#pragma unroll
            for (int reg = 0; reg < 4; ++reg) {
                int tl = wm * 64 + bi * 16 + (lane >> 4) * 4 + reg;
                tokmin[tl * 2 + wn] = pmin[reg];
            }
        }
    }
    __syncthreads();

    if (tid < 128) {
        int tl = tid;
        u64 bm = tokmin[tl * 2], b1 = tokmin[tl * 2 + 1];
        if (b1 < bm) bm = b1;
        u64 old = atomicMin(&packed[t0 + tl], bm);
        u64 gb = (old < bm) ? old : bm;
        float d_bmin = __uint_as_float((unsigned)(bm >> 32));
        bmf[tl] = -100.f * d_bmin;
        bthr[tl] = __uint_as_float((unsigned)(gb >> 32)) + DCUT;
    }
    __syncthreads();

#pragma unroll
    for (int bi = 0; bi < 4; ++bi) {
        float ez[4] = {0.f, 0.f, 0.f, 0.f}, ew[4] = {0.f, 0.f, 0.f, 0.f};
        f32x4 z4 = *reinterpret_cast<const f32x4*>(
            &z2s[t0 + wm * 64 + bi * 16 + (lane >> 4) * 4]);
#pragma unroll
        for (int reg = 0; reg < 4; ++reg) {
            int tl = wm * 64 + bi * 16 + (lane >> 4) * 4 + reg;
            int t = t0 + tl;
            float m_b = bmf[tl], thr = bthr[tl];
#pragma unroll
            for (int bj = 0; bj < 4; ++bj) {
                float d = z4[reg] + e2sv[bj] + acc[bi][bj][reg];
                float a = -100.f * d;
                float e = __expf(a - m_b);
                ez[reg] += e;
                ew[reg] = fmaf(a, e, ew[reg]);
                if (d <= thr) {
                    int pos = atomicAdd(&ncand[t], 1);
                    if (pos < CAP) {
                        candD[(size_t)t * CAP + pos] = d;
                        candN[(size_t)t * CAP + pos] = n0 + wn * 64 + bj * 16 + (lane & 15);
                    }
                }
            }
        }
#pragma unroll
        for (int m = 1; m < 16; m <<= 1)
#pragma unroll
            for (int reg = 0; reg < 4; ++reg) {
                ez[reg] += __shfl_xor(ez[reg], m, 64);
                ew[reg] += __shfl_xor(ew[reg], m, 64);
            }
        if ((lane & 15) == 0) {
#pragma unroll
            for (int reg = 0; reg < 4; ++reg) {
                int tl = wm * 64 + bi * 16 + (lane >> 4) * 4 + reg;
                pzw[(tl * 2 + wn) * 2 + 0] = ez[reg];
                pzw[(tl * 2 + wn) * 2 + 1] = ew[reg];
            }
        }
    }
    __syncthreads();

    if (tid < 128) {
        int tl = tid;
        size_t o = (size_t)(gid >> 5) * T_TOK + t0 + tl;
        part_m[o] = bmf[tl];
        part_z[o] = pzw[tl * 4 + 0] + pzw[tl * 4 + 2];
        part_w[o] = pzw[tl * 4 + 1] + pzw[tl * 4 + 3];
    }
}

// ---------------- combine + zq + scatter + last-block finalize ----------------
// 128 blocks x 32 tokens.
__global__ __launch_bounds__(256)
void combine_final_kernel(const float* __restrict__ part_m, const float* __restrict__ part_z,
                          const float* __restrict__ part_w, const u64* __restrict__ packed,
                          const float* __restrict__ enorm, const float* __restrict__ znorm,
                          const float* __restrict__ candD, const int* __restrict__ candN,
                          const int* __restrict__ ncand, float* __restrict__ avg_num,
                          float* __restrict__ scal, int* __restrict__ done_ctr,
                          const float* __restrict__ G, const float* __restrict__ SV,
                          const float* __restrict__ mom, float* __restrict__ out) {
    __shared__ float sm[32][8], sz[32][8], sw[32][8];
    __shared__ float Ms[32], Zts[32];
    __shared__ int idxs[32];
    __shared__ float q_lds[256][33];
    __shared__ float red[256];
    __shared__ int lastf;
    int tid = threadIdx.x, tl = tid & 31, q = tid >> 5;   // 8 groups x 16 n-blocks
    int tbase = blockIdx.x * 32;
    int t = tbase + tl;

    // phase 1: online-softmax combine (8-way split over 128 n-blocks)
    float m = -3.0e38f, Z = 0.f, W = 0.f;
    for (int nb = q * 16; nb < q * 16 + 16; ++nb) {
        size_t o = (size_t)nb * T_TOK + t;
        float mb = part_m[o], zb = part_z[o], wb = part_w[o];
        if (mb > m) { float s = __expf(m - mb); Z *= s; W *= s; m = mb; }
        float s2 = __expf(mb - m);
        Z = fmaf(zb, s2, Z); W = fmaf(wb, s2, W);
    }
    sm[tl][q] = m; sz[tl][q] = Z; sw[tl][q] = W;
    __syncthreads();
    if (tid < 32) {
        float M = sm[tid][0], Zt = sz[tid][0], Wt = sw[tid][0];
#pragma unroll
        for (int qq = 1; qq < 8; ++qq) {
            float mb = sm[tid][qq], Zb = sz[tid][qq], Wb = sw[tid][qq];
            if (mb > M) { float s = __expf(M - mb); Zt *= s; Wt *= s; M = mb; }
            float s2 = __expf(mb - M);
            Zt = fmaf(Zb, s2, Zt); Wt = fmaf(Wb, s2, Wt);
        }
        int tt = tbase + tid;
        Ms[tid] = M; Zts[tid] = Zt;
        u64 pv = packed[tt];
        int idx = (int)(pv & 0xFFFFFFFFull);
        idxs[tid] = idx;
        out[1048581 + tt] = (float)idx;
        float ent = M + logf(Zt) - Wt / Zt;
#pragma unroll
        for (int mm = 1; mm < 32; mm <<= 1) ent += __shfl_xor(ent, mm, 64);
        if (tid == 0) atomicAdd(&scal[3], ent);
    }
    __syncthreads();

    // phase 2: z_q gather + transpose + vq loss (32 tokens)
    float sdq = 0.f;
    for (int tl2 = 0; tl2 < 32; ++tl2) {
        int tt = tbase + tl2;
        float qv = enorm[(size_t)idxs[tl2] * KD + tid];
        q_lds[tid][tl2] = qv;
        float zc = znorm[(size_t)tt * KD + tid];
        float df = qv - zc;
        sdq = fmaf(df, df, sdq);
    }
    __syncthreads();
    {
        int bb = tbase >> 10, hw0 = tbase & 1023;
        int cg = tid >> 5, hwl = tid & 31;
        for (int c0 = 0; c0 < 256; c0 += 8) {
            int c = c0 + cg;
            out[(((size_t)(bb * 256 + c)) << 10) + hw0 + hwl] = q_lds[c][hwl];
        }
    }
    red[tid] = sdq;
    __syncthreads();
    for (int s = 128; s > 0; s >>= 1) { if (tid < s) red[tid] += red[tid + s]; __syncthreads(); }
    if (tid == 0) atomicAdd(&scal[2], red[0]);

    // phase 3: avg_probs scatter (8 lanes per token)
    {
        int tok = tid >> 3, sub = tid & 7;
        int tt = tbase + tok;
        int nc = min(ncand[tt], CAP);
        float M = Ms[tok], Zt = Zts[tok];
        for (int i = sub; i < nc; i += 8) {
            float a = -100.f * candD[(size_t)tt * CAP + i];
            atomicAdd(&avg_num[candN[(size_t)tt * CAP + i]], __expf(a - M) / Zt);
        }
    }

    // phase 4: last block does finalize
    __syncthreads();
    __threadfence();
    if (tid == 0) lastf = (atomicAdd(done_ctr, 1) == 127) ? 1 : 0;
    __syncthreads();
    if (!lastf) return;
    __threadfence();

    // avg_probs entropy (device-scope atomic reads for cross-XCD safety)
    float s = 0.f;
    for (int n = tid; n < NE; n += 256) {
        float avg = atomicAdd(&avg_num[n], 0.f) * (1.f / 4096.f);
        s += avg * logf(avg + 1e-5f);
    }
    red[tid] = s; __syncthreads();
    for (int st = 128; st > 0; st >>= 1) { if (tid < st) red[tid] += red[tid + st]; __syncthreads(); }
    float avg_ent_neg = red[0];
    __syncthreads();

    const float* G_ek = G;
    const float* G_eg = G + 4096;
    const float* G_zk = G + 40960;
    const float* G_zg = G + 45056;
    float rk = 0.f, rg = 0.f;
    for (int i = tid; i < 4096; i += 256)  rk = fmaf(G_zk[i], G_ek[i], rk);
    for (int i = tid; i < 36864; i += 256) rg = fmaf(G_zg[i], G_eg[i], rg);
    {
        int c = tid;
        float v = SV[256 + c] * SV[512 + c] + SV[c] * SV[768 + c];
        if (c < 64) rk -= v; else rg -= v;
    }
    red[tid] = 4.f * rk; __syncthreads();
    for (int st = 128; st > 0; st >>= 1) { if (tid < st) red[tid] += red[tid + st]; __syncthreads(); }
    float red_k = red[0];
    __syncthreads();
    red[tid] = 4.f * rg; __syncthreads();
    for (int st = 128; st > 0; st >>= 1) { if (tid < st) red[tid] += red[tid + st]; __syncthreads(); }
    float red_g = red[0];

    if (tid == 0) {
        float term1k = NE * mom[1] + 2.f * mom[0] * mom[4] + T_TOK * mom[5];
        float term1g = NE * mom[3] + 2.f * mom[2] * mom[6] + T_TOK * mom[7];
        float sdk2 = term1k + red_k;
        float sdg2 = term1g + red_g;
        float avg_ent = -avg_ent_neg;
        float se = atomicAdd(&scal[3], 0.f) * (1.f / 4096.f);
        float vq = atomicAdd(&scal[2], 0.f) * (1.f / 1048576.f);
        out[1048576] = vq;
        out[1048577] = 0.25f * vq;
        out[1048578] = 0.1f * (se - avg_ent);
        out[1048579] = sdk2 * (1.f / 4096.f);
        out[1048580] = sdg2 * (1.f / 4096.f);
    }
}

// ---------------- host ----------------
extern "C" void kernel_launch(void* const* d_in, const int* in_sizes, int n_in,
                              void* d_out, int out_size, void* d_ws, size_t ws_size,
                              hipStream_t stream) {
    const float* z  = (const float*)d_in[0];
    const float* wk = (const float*)d_in[1];
    const float* wg = (const float*)d_in[2];
    float* out = (float*)d_out;

    char* ws = (char*)d_ws;
    size_t off = 0;
    auto alloc = [&](size_t bytes) {
        void* p = ws + off;
        off += (bytes + 255) & ~(size_t)255;
        return p;
    };
    float* enorm  = (float*)alloc((size_t)NE * KD * 4);
    float* znorm  = (float*)alloc((size_t)T_TOK * KD * 4);
    short* Es     = (short*)alloc((size_t)NE * K3 * 2);
    short* Zs     = (short*)alloc((size_t)T_TOK * K3 * 2);
    float* e2k    = (float*)alloc(NE * 4);
    float* e2s    = (float*)alloc(NE * 4);
    float* z2k    = (float*)alloc(T_TOK * 4);
    float* z2s    = (float*)alloc(T_TOK * 4);
    u64*   packed = (u64*)alloc(T_TOK * 8);
    int*   ncand  = (int*)alloc(T_TOK * 4);
    float* part_m = (float*)alloc((size_t)(NE / 128) * T_TOK * 4);
    float* part_z = (float*)alloc((size_t)(NE / 128) * T_TOK * 4);
    float* part_w = (float*)alloc((size_t)(NE / 128) * T_TOK * 4);
    float* candD  = (float*)alloc((size_t)T_TOK * CAP * 4);
    int*   candN  = (int*)alloc((size_t)T_TOK * CAP * 4);
    float* avg_num= (float*)alloc(NE * 4);
    float* scal   = (float*)alloc(8 * 4);
    float* Gbuf   = (float*)alloc(81920 * 4);
    float* SV     = (float*)alloc(1024 * 4);
    float* momv   = (float*)alloc(8 * 4);
    float* SVeS   = (float*)alloc((size_t)NCB * 256 * 4);
    float* SVeV   = (float*)alloc((size_t)NCB * 256 * 4);
    float* SVzS   = (float*)alloc((size_t)NZB * 256 * 4);
    float* SVzV   = (float*)alloc((size_t)NZB * 256 * 4);
    float* mompart= (float*)alloc((size_t)(NCB + NZB) * 4 * 4);
    int*   done_ctr = (int*)alloc(256);

    megaprep_kernel<<<NCB + NZB + 8, 256, 0, stream>>>(
        wk, wg, z, enorm, e2k, e2s, Es, znorm, z2k, z2s, Zs,
        SVeS, SVeV, SVzS, SVzV, mompart, packed, avg_num, ncand, scal, Gbuf, done_ctr);

    gemm_gram_kernel<<<NGEMM + 402, 256, 0, stream>>>(
        Zs, Es, z2s, e2s, packed, scal, part_m, part_z, part_w,
        candD, candN, ncand, znorm, enorm, Gbuf,
        SVeS, SVeV, SVzS, SVzV, mompart, SV, momv);

    combine_final_kernel<<<T_TOK / 32, 256, 0, stream>>>(
        part_m, part_z, part_w, packed, enorm, znorm,
        candD, candN, ncand, avg_num, scal, done_ctr, Gbuf, SV, momv, out);
}

// Round 10
// 361.660 us; speedup vs baseline: 1.3090x; 1.1399x over previous
//
#include <hip/hip_runtime.h>

// VectorQuantizer forward, MI355X. Split-bf16 MFMA GEMM (hi/lo, 3 products,
// K extended 256->768). Epilogue: argmin + per-block online-softmax partials
// (exact entropy) + racy-shrinking-threshold candidate capture. d^2-norm split
// in closed form (Gram + colsums + moments). R10: gram blocks placed at HEAD
// of the gemm dispatch (co-scheduled VALU vs MFMA, m114) and retiled as
// 32-col-strip x full-width jobs (2.8x fewer re-reads). 3 kernels total.
// T=4096 tokens, NE=16384 codes.

#define T_TOK 4096
#define NE    16384
#define KD    256
#define K3    768          // 3x split-extended K
#define CAP   768          // candidate slots per token (avg_probs only)
#define DCUT  0.15f        // capture window above best-so-far global min

#define NCB   512          // code prep blocks (32 rows each)
#define NZB   128          // z prep blocks (32 tokens each)
#define NGRAM 142          // gram strip jobs + 2 reduce blocks (placed first)
#define NGEMM 4096         // gemm blocks (32 x 128)

typedef __attribute__((ext_vector_type(8))) short bf16x8;
typedef __attribute__((ext_vector_type(4))) float f32x4;
typedef unsigned long long u64;

__device__ __forceinline__ short f2bf(float f) {
    unsigned u = __float_as_uint(f);
    u = (u + 0x7FFFu + ((u >> 16) & 1u)) >> 16;   // round-to-nearest-even
    return (short)u;
}
__device__ __forceinline__ float bf2f(short s) {
    return __uint_as_float(((unsigned)(unsigned short)s) << 16);
}

__device__ __forceinline__ void async_load16(const void* g, void* l) {
    __builtin_amdgcn_global_load_lds(
        (const __attribute__((address_space(1))) void*)g,
        (__attribute__((address_space(3))) void*)l, 16, 0, 0);
}

// ---------------- megaprep: codes | z | init, branch on blockIdx ----------------
__global__ __launch_bounds__(256)
void megaprep_kernel(const float* __restrict__ wk, const float* __restrict__ wg,
                     const float* __restrict__ z,
                     float* __restrict__ enorm, float* __restrict__ e2k,
                     float* __restrict__ e2s, short* __restrict__ Es,
                     float* __restrict__ znorm, float* __restrict__ z2k,
                     float* __restrict__ z2s, short* __restrict__ Zs,
                     float* __restrict__ SVeS, float* __restrict__ SVeV,
                     float* __restrict__ SVzS, float* __restrict__ SVzV,
                     float* __restrict__ mompart,
                     u64* __restrict__ packed, float* __restrict__ avg_num,
                     int* __restrict__ ncand, float* __restrict__ scal,
                     float* __restrict__ G, int* __restrict__ done_ctr) {
    int b = blockIdx.x, tid = threadIdx.x;
    if (b >= NCB + NZB) {                    // ---- init branch ----
        int gid = (b - NCB - NZB) * 256 + tid;
        for (int i = gid; i < 81920; i += 2048) G[i] = 0.f;
        for (int i = gid; i < NE; i += 2048) avg_num[i] = 0.f;
        for (int i = gid; i < T_TOK; i += 2048) { packed[i] = ~0ull; ncand[i] = 0; }
        if (gid < 8) scal[gid] = 0.f;
        if (gid == 8) *done_ctr = 0;
        return;
    }

    __shared__ float xs[32][257];            // 32.9 KB
    __shared__ float ps[32][8];
    __shared__ float rnorm[32][2];
    __shared__ float rw[32][2];

    if (b < NCB) {                           // ---- codes branch ----
        int n0 = b * 32;
#pragma unroll
        for (int i = 0; i < 8; ++i) {
            int idx = tid + i * 256;
            xs[idx >> 6][idx & 63] = wk[(size_t)n0 * 64 + idx];
        }
#pragma unroll
        for (int i = 0; i < 24; ++i) {
            int idx = tid + i * 256;
            xs[idx / 192][64 + idx % 192] = wg[(size_t)n0 * 192 + idx];
        }
        __syncthreads();
        {
            int r = tid & 31, part = tid >> 5;
            float s = 0.f;
            for (int j = 0; j < 32; ++j) { float v = xs[r][part * 32 + j]; s = fmaf(v, v, s); }
            ps[r][part] = s;
        }
        __syncthreads();
        if (tid < 32) {
            float sk = ps[tid][0] + ps[tid][1];
            float sg = ps[tid][2] + ps[tid][3] + ps[tid][4] + ps[tid][5] + ps[tid][6] + ps[tid][7];
            float nk = fmaxf(sqrtf(sk), 1e-12f), ng = fmaxf(sqrtf(sg), 1e-12f);
            float ek2 = sk / (nk * nk), eg2 = sg / (ng * ng);
            rnorm[tid][0] = 1.f / nk; rnorm[tid][1] = 1.f / ng;
            rw[tid][0] = ek2; rw[tid][1] = eg2;
            e2k[n0 + tid] = ek2; e2s[n0 + tid] = ek2 + eg2;
        }
        __syncthreads();
        int c = tid;
        for (int i = 0; i < 32; ++i) {
            float y = xs[i][c] * rnorm[i][(c < 64) ? 0 : 1];
            enorm[(size_t)(n0 + i) * KD + c] = y;
            short h = f2bf(y);          float hf = bf2f(h);
            short l = f2bf(y - hf);
            short sh = f2bf(-2.f * hf), sl = f2bf(-2.f * bf2f(l));
            short* Er = Es + (size_t)(n0 + i) * K3;
            if (c < 64) { Er[c] = sh; Er[64 + c] = sl; Er[128 + c] = sh; }
            else { int cc = c - 64; Er[192 + cc] = sh; Er[384 + cc] = sl; Er[576 + cc] = sh; }
        }
        {
            int sel = (c < 64) ? 0 : 1;
            float S = 0.f, V = 0.f;
            for (int r = 0; r < 32; ++r) {
                float y = xs[r][c] * rnorm[r][sel];
                S += y; V = fmaf(rw[r][sel], y, V);
            }
            SVeS[(size_t)b * 256 + c] = S;
            SVeV[(size_t)b * 256 + c] = V;
        }
        if (tid < 32) {
            float a = rw[tid][0], g = rw[tid][1];
            float s0 = a, s1 = a * a, s2 = g, s3 = g * g;
#pragma unroll
            for (int m = 1; m < 32; m <<= 1) {
                s0 += __shfl_xor(s0, m, 64); s1 += __shfl_xor(s1, m, 64);
                s2 += __shfl_xor(s2, m, 64); s3 += __shfl_xor(s3, m, 64);
            }
            if (tid == 0) {
                mompart[b * 4 + 0] = s0; mompart[b * 4 + 1] = s1;
                mompart[b * 4 + 2] = s2; mompart[b * 4 + 3] = s3;
            }
        }
    } else {                                 // ---- z branch ----
        int jz = b - NCB;
        int t0 = jz * 32;
        int bb = t0 >> 10, hw0 = t0 & 1023;
#pragma unroll
        for (int i = 0; i < 32; ++i) {
            int idx = tid + i * 256;
            int cc = idx >> 5, hwl = idx & 31;
            xs[hwl][cc] = z[(((size_t)bb * 256 + cc) << 10) + hw0 + hwl];
        }
        __syncthreads();
        {
            int r = tid & 31, part = tid >> 5;
            float s = 0.f;
            for (int j = 0; j < 32; ++j) { float v = xs[r][part * 32 + j]; s = fmaf(v, v, s); }
            ps[r][part] = s;
        }
        __syncthreads();
        if (tid < 32) {
            float sk = ps[tid][0] + ps[tid][1];
            float sg = ps[tid][2] + ps[tid][3] + ps[tid][4] + ps[tid][5] + ps[tid][6] + ps[tid][7];
            float nk = fmaxf(sqrtf(sk), 1e-12f), ng = fmaxf(sqrtf(sg), 1e-12f);
            float zk2 = sk / (nk * nk), zg2 = sg / (ng * ng);
            rnorm[tid][0] = 1.f / nk; rnorm[tid][1] = 1.f / ng;
            rw[tid][0] = zk2; rw[tid][1] = zg2;
            z2k[t0 + tid] = zk2; z2s[t0 + tid] = zk2 + zg2;
        }
        __syncthreads();
        int c = tid;
        for (int i = 0; i < 32; ++i) {
            float y = xs[i][c] * rnorm[i][(c < 64) ? 0 : 1];
            znorm[(size_t)(t0 + i) * KD + c] = y;
            short h = f2bf(y);      float hf = bf2f(h);
            short l = f2bf(y - hf);
            short* Zr = Zs + (size_t)(t0 + i) * K3;
            if (c < 64) { Zr[c] = h; Zr[64 + c] = h; Zr[128 + c] = l; }
            else { int cc = c - 64; Zr[192 + cc] = h; Zr[384 + cc] = h; Zr[576 + cc] = l; }
        }
        {
            int sel = (c < 64) ? 0 : 1;
            float S = 0.f, V = 0.f;
            for (int r = 0; r < 32; ++r) {
                float y = xs[r][c] * rnorm[r][sel];
                S += y; V = fmaf(rw[r][sel], y, V);
            }
            SVzS[(size_t)jz * 256 + c] = S;
            SVzV[(size_t)jz * 256 + c] = V;
        }
        if (tid < 32) {
            float a = rw[tid][0], g = rw[tid][1];
            float s0 = a, s1 = a * a, s2 = g, s3 = g * g;
#pragma unroll
            for (int m = 1; m < 32; m <<= 1) {
                s0 += __shfl_xor(s0, m, 64); s1 += __shfl_xor(s1, m, 64);
                s2 += __shfl_xor(s2, m, 64); s3 += __shfl_xor(s3, m, 64);
            }
            if (tid == 0) {
                mompart[b * 4 + 0] = s0; mompart[b * 4 + 1] = s1;
                mompart[b * 4 + 2] = s2; mompart[b * 4 + 3] = s3;
            }
        }
    }
}

// ---------------- gram strip job: 32-col i-strip x full W, register acc ----------------
template <int W>
__device__ __forceinline__ void gram_strip(const float* __restrict__ X, float* __restrict__ G,
                                           int i0s, int r0, int rows, int c0,
                                           float* xs, int tid) {
    const int JW = W / 32;                    // 6 (W=192) or 2 (W=64)
    int ia = tid >> 5;                        // 0..7 -> i sub (4 cols)
    int jb = tid & 31;                        // 0..31 -> j group (JW cols)
    float acc[4][JW];
#pragma unroll
    for (int a = 0; a < 4; ++a)
#pragma unroll
        for (int u = 0; u < JW; ++u) acc[a][u] = 0.f;
    for (int rb = 0; rb < rows; rb += 16) {
        __syncthreads();
        for (int lin = tid; lin < 4 * W; lin += 256) {
            int r = lin / (W / 4), f4 = lin % (W / 4);
            *(float4*)&xs[r * W + f4 * 4] =
                *(const float4*)&X[(size_t)(r0 + rb + r) * KD + c0 + f4 * 4];
        }
        __syncthreads();
#pragma unroll 4
        for (int r = 0; r < 16; ++r) {
            float4 xi = *(const float4*)&xs[r * W + i0s + ia * 4];
            float xj[JW];
#pragma unroll
            for (int u = 0; u < JW; ++u) xj[u] = xs[r * W + jb * JW + u];
#pragma unroll
            for (int a = 0; a < 4; ++a)
#pragma unroll
                for (int u = 0; u < JW; ++u)
                    acc[a][u] = fmaf(xi[a], xj[u], acc[a][u]);
        }
    }
#pragma unroll
    for (int a = 0; a < 4; ++a) {
        int i = i0s + ia * 4 + a;
#pragma unroll
        for (int u = 0; u < JW; ++u)
            atomicAdd(&G[i * W + jb * JW + u], acc[a][u]);
    }
}

// ---------------- fused Gram (HEAD) + GEMM ----------------
// gid < NGRAM: gram strip jobs / reduces (overlap gemm's MFMA via co-scheduling).
// gid >= NGRAM: gemm, g=gid-NGRAM, t0=(g%32)*128, n0=(g/32)*128.
__global__ __launch_bounds__(256, 4)
void gemm_gram_kernel(const short* __restrict__ Zs, const short* __restrict__ Es,
                      const float* __restrict__ z2s, const float* __restrict__ e2s,
                      u64* __restrict__ packed, float* __restrict__ scal,
                      float* __restrict__ part_m, float* __restrict__ part_z,
                      float* __restrict__ part_w,
                      float* __restrict__ candD, int* __restrict__ candN,
                      int* __restrict__ ncand,
                      const float* __restrict__ znorm, const float* __restrict__ enorm,
                      float* __restrict__ Gbuf,
                      const float* __restrict__ SVeS, const float* __restrict__ SVeV,
                      const float* __restrict__ SVzS, const float* __restrict__ SVzV,
                      const float* __restrict__ mompart,
                      float* __restrict__ SV, float* __restrict__ mom) {
    __shared__ __align__(16) char smem[32768];
    const int gid = blockIdx.x, tid = threadIdx.x;

    if (gid < NGRAM) {                        // =============== GRAM path ===============
        int b = gid;
        float* xs = (float*)smem;             // 12.3 KB max
        float* r1 = (float*)(smem + 12288);
        float* r2 = (float*)(smem + 13312);

        if (b == 140) {                       // SV reduce
            int c = tid;
            float s = 0.f, v = 0.f;
            for (int j = 0; j < NZB; ++j) { s += SVzS[(size_t)j * 256 + c]; v += SVzV[(size_t)j * 256 + c]; }
            SV[c] = s; SV[256 + c] = v;
            s = 0.f; v = 0.f;
            for (int j = 0; j < NCB; ++j) { s += SVeS[(size_t)j * 256 + c]; v += SVeV[(size_t)j * 256 + c]; }
            SV[512 + c] = s; SV[768 + c] = v;
            return;
        }
        if (b == 141) {                       // moments reduce
            int q = tid & 3, grp = tid >> 2;
            float accE = 0.f, accZ = 0.f;
            for (int j = grp; j < NCB; j += 64) accE += mompart[j * 4 + q];
            for (int j = NCB + grp; j < NCB + NZB; j += 64) accZ += mompart[j * 4 + q];
            r1[tid] = accE; r2[tid] = accZ;
            __syncthreads();
            for (int st = 32; st > 0; st >>= 1) {
                if (grp < st) { r1[tid] += r1[tid + st * 4]; r2[tid] += r2[tid + st * 4]; }
                __syncthreads();
            }
            if (grp == 0) { mom[4 + q] = r1[q]; mom[q] = r2[q]; }
            return;
        }
        // strip jobs: [0,96) E-g | [96,112) E-k | [112,136) Z-g | [136,140) Z-k
        if (b < 96) {
            gram_strip<192>(enorm, Gbuf + 4096, (b >> 4) * 32, (b & 15) * 1024, 1024, 64, xs, tid);
        } else if (b < 112) {
            int l = b - 96;
            gram_strip<64>(enorm, Gbuf, (l >> 3) * 32, (l & 7) * 2048, 2048, 0, xs, tid);
        } else if (b < 136) {
            int l = b - 112;
            gram_strip<192>(znorm, Gbuf + 45056, (l >> 2) * 32, (l & 3) * 1024, 1024, 64, xs, tid);
        } else {
            int l = b - 136;
            gram_strip<64>(znorm, Gbuf + 40960, (l >> 1) * 32, (l & 1) * 2048, 2048, 0, xs, tid);
        }
        return;
    }

    // =============== GEMM path ===============
    short* As = (short*)smem;                 // [128][64]
    short* Bs = As + 128 * 64;
    const int g = gid - NGRAM;
    const int lane = tid & 63, wid = tid >> 6;
    const int wm = wid >> 1, wn = wid & 1;
    const int t0 = (g & 31) * 128, n0 = (g >> 5) * 128;

    f32x4 acc[4][4];
#pragma unroll
    for (int bi = 0; bi < 4; ++bi)
#pragma unroll
        for (int bj = 0; bj < 4; ++bj) {
            f32x4 zz = {0.f, 0.f, 0.f, 0.f};
            acc[bi][bj] = zz;
        }

    auto stage = [&](int k0) {
        const int rb0 = wid * 32;
#pragma unroll
        for (int c2 = 0; c2 < 4; ++c2) {
            int rb = rb0 + c2 * 8;
            int row = rb + (lane >> 3);
            int q = (lane & 7) ^ (lane >> 3);   // XOR-quad swizzle (rb%8==0)
            async_load16(Zs + (size_t)(t0 + row) * K3 + k0 + q * 8, &As[rb * 64]);
            async_load16(Es + (size_t)(n0 + row) * K3 + k0 + q * 8, &Bs[rb * 64]);
        }
    };
    auto compute_half = [&](int s) {
        bf16x8 bfv[4];
#pragma unroll
        for (int bj = 0; bj < 4; ++bj) {
            int brow = wn * 64 + bj * 16 + (lane & 15);
            int q = ((s << 2) | (lane >> 4)) ^ (brow & 7);
            bfv[bj] = *reinterpret_cast<const bf16x8*>(&Bs[brow * 64 + q * 8]);
        }
#pragma unroll
        for (int bi = 0; bi < 4; ++bi) {
            int arow = wm * 64 + bi * 16 + (lane & 15);
            int q = ((s << 2) | (lane >> 4)) ^ (arow & 7);
            bf16x8 af = *reinterpret_cast<const bf16x8*>(&As[arow * 64 + q * 8]);
#pragma unroll
            for (int bj = 0; bj < 4; ++bj)
                acc[bi][bj] = __builtin_amdgcn_mfma_f32_16x16x32_bf16(
                    af, bfv[bj], acc[bi][bj], 0, 0, 0);
        }
    };

    int k0 = 0;
    for (int r = 0; r < 12; ++r) {
        stage(k0); __syncthreads();
        compute_half(0); compute_half(1);
        __syncthreads(); k0 += 64;
    }

    // ---- epilogue ----
    u64*   tokmin = (u64*)smem;               // [128][2]   2048 B
    float* bmf    = (float*)(smem + 2048);    // [128]
    float* bthr   = (float*)(smem + 2560);    // [128]
    float* pzw    = (float*)(smem + 3072);    // [128][2][2]

    float e2sv[4];
#pragma unroll
    for (int bj = 0; bj < 4; ++bj)
        e2sv[bj] = e2s[n0 + wn * 64 + bj * 16 + (lane & 15)];

#pragma unroll
    for (int bi = 0; bi < 4; ++bi) {
        u64 pmin[4] = {~0ull, ~0ull, ~0ull, ~0ull};
        f32x4 z4 = *reinterpret_cast<const f32x4*>(
            &z2s[t0 + wm * 64 + bi * 16 + (lane >> 4) * 4]);
#pragma unroll
        for (int reg = 0; reg < 4; ++reg) {
#pragma unroll
            for (int bj = 0; bj < 4; ++bj) {
                float d = z4[reg] + e2sv[bj] + acc[bi][bj][reg];
                int n = n0 + wn * 64 + bj * 16 + (lane & 15);
                u64 pv = (((u64)__float_as_uint(d)) << 32) | (unsigned)n;
                if (pv < pmin[reg]) pmin[reg] = pv;
            }
        }
#pragma unroll
        for (int m = 1; m < 16; m <<= 1)
#pragma unroll
            for (int reg = 0; reg < 4; ++reg) {
                u64 o = __shfl_xor(pmin[reg], m, 64);
                if (o < pmin[reg]) pmin[reg] = o;
            }
        if ((lane & 15) == 0) {
#pragma unroll
            for (int reg = 0; reg < 4; ++reg) {
                int tl = wm * 64 + bi * 16 + (lane >> 4) * 4 + reg;
                tokmin[tl * 2 + wn] = pmin[reg];
            }
        }
    }
    __syncthreads();

    if (tid < 128) {
        int tl = tid;
        u64 bm = tokmin[tl * 2], b1 = tokmin[tl * 2 + 1];
        if (b1 < bm) bm = b1;
        u64 old = atomicMin(&packed[t0 + tl], bm);
        u64 gb = (old < bm) ? old : bm;
        float d_bmin = __uint_as_float((unsigned)(bm >> 32));
        bmf[tl] = -100.f * d_bmin;
        bthr[tl] = __uint_as_float((unsigned)(gb >> 32)) + DCUT;
    }
    __syncthreads();

#pragma unroll
    for (int bi = 0; bi < 4; ++bi) {
        float ez[4] = {0.f, 0.f, 0.f, 0.f}, ew[4] = {0.f, 0.f, 0.f, 0.f};
        f32x4 z4 = *reinterpret_cast<const f32x4*>(
            &z2s[t0 + wm * 64 + bi * 16 + (lane >> 4) * 4]);
#pragma unroll
        for (int reg = 0; reg < 4; ++reg) {
            int tl = wm * 64 + bi * 16 + (lane >> 4) * 4 + reg;
            int t = t0 + tl;
            float m_b = bmf[tl], thr = bthr[tl];
#pragma unroll
            for (int bj = 0; bj < 4; ++bj) {
                float d = z4[reg] + e2sv[bj] + acc[bi][bj][reg];
                float a = -100.f * d;
                float e = __expf(a - m_b);
                ez[reg] += e;
                ew[reg] = fmaf(a, e, ew[reg]);
                if (d <= thr) {
                    int pos = atomicAdd(&ncand[t], 1);
                    if (pos < CAP) {
                        candD[(size_t)t * CAP + pos] = d;
                        candN[(size_t)t * CAP + pos] = n0 + wn * 64 + bj * 16 + (lane & 15);
                    }
                }
            }
        }
#pragma unroll
        for (int m = 1; m < 16; m <<= 1)
#pragma unroll
            for (int reg = 0; reg < 4; ++reg) {
                ez[reg] += __shfl_xor(ez[reg], m, 64);
                ew[reg] += __shfl_xor(ew[reg], m, 64);
            }
        if ((lane & 15) == 0) {
#pragma unroll
            for (int reg = 0; reg < 4; ++reg) {
                int tl = wm * 64 + bi * 16 + (lane >> 4) * 4 + reg;
                pzw[(tl * 2 + wn) * 2 + 0] = ez[reg];
                pzw[(tl * 2 + wn) * 2 + 1] = ew[reg];
            }
        }
    }
    __syncthreads();

    if (tid < 128) {
        int tl = tid;
        size_t o = (size_t)(g >> 5) * T_TOK + t0 + tl;
        part_m[o] = bmf[tl];
        part_z[o] = pzw[tl * 4 + 0] + pzw[tl * 4 + 2];
        part_w[o] = pzw[tl * 4 + 1] + pzw[tl * 4 + 3];
    }
}

// ---------------- combine + zq + scatter + last-block finalize ----------------
// 128 blocks x 32 tokens.
__global__ __launch_bounds__(256)
void combine_final_kernel(const float* __restrict__ part_m, const float* __restrict__ part_z,
                          const float* __restrict__ part_w, const u64* __restrict__ packed,
                          const float* __restrict__ enorm, const float* __restrict__ znorm,
                          const float* __restrict__ candD, const int* __restrict__ candN,
                          const int* __restrict__ ncand, float* __restrict__ avg_num,
                          float* __restrict__ scal, int* __restrict__ done_ctr,
                          const float* __restrict__ G, const float* __restrict__ SV,
                          const float* __restrict__ mom, float* __restrict__ out) {
    __shared__ float sm[32][8], sz[32][8], sw[32][8];
    __shared__ float Ms[32], Zts[32];
    __shared__ int idxs[32];
    __shared__ float q_lds[256][33];
    __shared__ float red[256];
    __shared__ int lastf;
    int tid = threadIdx.x, tl = tid & 31, q = tid >> 5;   // 8 groups x 16 n-blocks
    int tbase = blockIdx.x * 32;
    int t = tbase + tl;

    // phase 1: online-softmax combine (8-way split over 128 n-blocks)
    float m = -3.0e38f, Z = 0.f, W = 0.f;
    for (int nb = q * 16; nb < q * 16 + 16; ++nb) {
        size_t o = (size_t)nb * T_TOK + t;
        float mb = part_m[o], zb = part_z[o], wb = part_w[o];
        if (mb > m) { float s = __expf(m - mb); Z *= s; W *= s; m = mb; }
        float s2 = __expf(mb - m);
        Z = fmaf(zb, s2, Z); W = fmaf(wb, s2, W);
    }
    sm[tl][q] = m; sz[tl][q] = Z; sw[tl][q] = W;
    __syncthreads();
    if (tid < 32) {
        float M = sm[tid][0], Zt = sz[tid][0], Wt = sw[tid][0];
#pragma unroll
        for (int qq = 1; qq < 8; ++qq) {
            float mb = sm[tid][qq], Zb = sz[tid][qq], Wb = sw[tid][qq];
            if (mb > M) { float s = __expf(M - mb); Zt *= s; Wt *= s; M = mb; }
            float s2 = __expf(mb - M);
            Zt = fmaf(Zb, s2, Zt); Wt = fmaf(Wb, s2, Wt);
        }
        int tt = tbase + tid;
        Ms[tid] = M; Zts[tid] = Zt;
        u64 pv = packed[tt];
        int idx = (int)(pv & 0xFFFFFFFFull);
        idxs[tid] = idx;
        out[1048581 + tt] = (float)idx;
        float ent = M + logf(Zt) - Wt / Zt;
#pragma unroll
        for (int mm = 1; mm < 32; mm <<= 1) ent += __shfl_xor(ent, mm, 64);
        if (tid == 0) atomicAdd(&scal[3], ent);
    }
    __syncthreads();

    // phase 2: z_q gather + transpose + vq loss (32 tokens)
    float sdq = 0.f;
    for (int tl2 = 0; tl2 < 32; ++tl2) {
        int tt = tbase + tl2;
        float qv = enorm[(size_t)idxs[tl2] * KD + tid];
        q_lds[tid][tl2] = qv;
        float zc = znorm[(size_t)tt * KD + tid];
        float df = qv - zc;
        sdq = fmaf(df, df, sdq);
    }
    __syncthreads();
    {
        int bb = tbase >> 10, hw0 = tbase & 1023;
        int cg = tid >> 5, hwl = tid & 31;
        for (int c0 = 0; c0 < 256; c0 += 8) {
            int c = c0 + cg;
            out[(((size_t)(bb * 256 + c)) << 10) + hw0 + hwl] = q_lds[c][hwl];
        }
    }
    red[tid] = sdq;
    __syncthreads();
    for (int s = 128; s > 0; s >>= 1) { if (tid < s) red[tid] += red[tid + s]; __syncthreads(); }
    if (tid == 0) atomicAdd(&scal[2], red[0]);

    // phase 3: avg_probs scatter (8 lanes per token)
    {
        int tok = tid >> 3, sub = tid & 7;
        int tt = tbase + tok;
        int nc = min(ncand[tt], CAP);
        float M = Ms[tok], Zt = Zts[tok];
        for (int i = sub; i < nc; i += 8) {
            float a = -100.f * candD[(size_t)tt * CAP + i];
            atomicAdd(&avg_num[candN[(size_t)tt * CAP + i]], __expf(a - M) / Zt);
        }
    }

    // phase 4: last block does finalize
    __syncthreads();
    __threadfence();
    if (tid == 0) lastf = (atomicAdd(done_ctr, 1) == 127) ? 1 : 0;
    __syncthreads();
    if (!lastf) return;
    __threadfence();

    // avg_probs entropy (device-scope atomic reads for cross-XCD safety)
    float s = 0.f;
    for (int n = tid; n < NE; n += 256) {
        float avg = atomicAdd(&avg_num[n], 0.f) * (1.f / 4096.f);
        s += avg * logf(avg + 1e-5f);
    }
    red[tid] = s; __syncthreads();
    for (int st = 128; st > 0; st >>= 1) { if (tid < st) red[tid] += red[tid + st]; __syncthreads(); }
    float avg_ent_neg = red[0];
    __syncthreads();

    const float* G_ek = G;
    const float* G_eg = G + 4096;
    const float* G_zk = G + 40960;
    const float* G_zg = G + 45056;
    float rk = 0.f, rg = 0.f;
    for (int i = tid; i < 4096; i += 256)  rk = fmaf(G_zk[i], G_ek[i], rk);
    for (int i = tid; i < 36864; i += 256) rg = fmaf(G_zg[i], G_eg[i], rg);
    {
        int c = tid;
        float v = SV[256 + c] * SV[512 + c] + SV[c] * SV[768 + c];
        if (c < 64) rk -= v; else rg -= v;
    }
    red[tid] = 4.f * rk; __syncthreads();
    for (int st = 128; st > 0; st >>= 1) { if (tid < st) red[tid] += red[tid + st]; __syncthreads(); }
    float red_k = red[0];
    __syncthreads();
    red[tid] = 4.f * rg; __syncthreads();
    for (int st = 128; st > 0; st >>= 1) { if (tid < st) red[tid] += red[tid + st]; __syncthreads(); }
    float red_g = red[0];

    if (tid == 0) {
        float term1k = NE * mom[1] + 2.f * mom[0] * mom[4] + T_TOK * mom[5];
        float term1g = NE * mom[3] + 2.f * mom[2] * mom[6] + T_TOK * mom[7];
        float sdk2 = term1k + red_k;
        float sdg2 = term1g + red_g;
        float avg_ent = -avg_ent_neg;
        float se = atomicAdd(&scal[3], 0.f) * (1.f / 4096.f);
        float vq = atomicAdd(&scal[2], 0.f) * (1.f / 1048576.f);
        out[1048576] = vq;
        out[1048577] = 0.25f * vq;
        out[1048578] = 0.1f * (se - avg_ent);
        out[1048579] = sdk2 * (1.f / 4096.f);
        out[1048580] = sdg2 * (1.f / 4096.f);
    }
}

// ---------------- host ----------------
extern "C" void kernel_launch(void* const* d_in, const int* in_sizes, int n_in,
                              void* d_out, int out_size, void* d_ws, size_t ws_size,
                              hipStream_t stream) {
    const float* z  = (const float*)d_in[0];
    const float* wk = (const float*)d_in[1];
    const float* wg = (const float*)d_in[2];
    float* out = (float*)d_out;

    char* ws = (char*)d_ws;
    size_t off = 0;
    auto alloc = [&](size_t bytes) {
        void* p = ws + off;
        off += (bytes + 255) & ~(size_t)255;
        return p;
    };
    float* enorm  = (float*)alloc((size_t)NE * KD * 4);
    float* znorm  = (float*)alloc((size_t)T_TOK * KD * 4);
    short* Es     = (short*)alloc((size_t)NE * K3 * 2);
    short* Zs     = (short*)alloc((size_t)T_TOK * K3 * 2);
    float* e2k    = (float*)alloc(NE * 4);
    float* e2s    = (float*)alloc(NE * 4);
    float* z2k    = (float*)alloc(T_TOK * 4);
    float* z2s    = (float*)alloc(T_TOK * 4);
    u64*   packed = (u64*)alloc(T_TOK * 8);
    int*   ncand  = (int*)alloc(T_TOK * 4);
    float* part_m = (float*)alloc((size_t)(NE / 128) * T_TOK * 4);
    float* part_z = (float*)alloc((size_t)(NE / 128) * T_TOK * 4);
    float* part_w = (float*)alloc((size_t)(NE / 128) * T_TOK * 4);
    float* candD  = (float*)alloc((size_t)T_TOK * CAP * 4);
    int*   candN  = (int*)alloc((size_t)T_TOK * CAP * 4);
    float* avg_num= (float*)alloc(NE * 4);
    float* scal   = (float*)alloc(8 * 4);
    float* Gbuf   = (float*)alloc(81920 * 4);
    float* SV     = (float*)alloc(1024 * 4);
    float* momv   = (float*)alloc(8 * 4);
    float* SVeS   = (float*)alloc((size_t)NCB * 256 * 4);
    float* SVeV   = (float*)alloc((size_t)NCB * 256 * 4);
    float* SVzS   = (float*)alloc((size_t)NZB * 256 * 4);
    float* SVzV   = (float*)alloc((size_t)NZB * 256 * 4);
    float* mompart= (float*)alloc((size_t)(NCB + NZB) * 4 * 4);
    int*   done_ctr = (int*)alloc(256);

    megaprep_kernel<<<NCB + NZB + 8, 256, 0, stream>>>(
        wk, wg, z, enorm, e2k, e2s, Es, znorm, z2k, z2s, Zs,
        SVeS, SVeV, SVzS, SVzV, mompart, packed, avg_num, ncand, scal, Gbuf, done_ctr);

    gemm_gram_kernel<<<NGRAM + NGEMM, 256, 0, stream>>>(
        Zs, Es, z2s, e2s, packed, scal, part_m, part_z, part_w,
        candD, candN, ncand, znorm, enorm, Gbuf,
        SVeS, SVeV, SVzS, SVzV, mompart, SV, momv);

    combine_final_kernel<<<T_TOK / 32, 256, 0, stream>>>(
        part_m, part_z, part_w, packed, enorm, znorm,
        candD, candN, ncand, avg_num, scal, done_ctr, Gbuf, SV, momv, out);
}